// Round 1
// baseline (1252.574 us; speedup 1.0000x reference)
//
#include <hip/hip_runtime.h>
#include <hip/hip_bf16.h>

#define NN 40000
#define NE 640000
#define DD 128
#define NPB 32      // nodes per block in fused kernel
#define SLOTS 8     // nodes processed per pass (256 threads / 32 per node)
#define WPAD 132    // padded LDS row stride (elements) to break bank conflicts
#define LN_EPS 1e-5f

// ---------- helpers ----------
__device__ inline unsigned short f2bf(float f) {
  union { float f; unsigned u; } v; v.f = f;
  unsigned r = v.u + 0x7FFFu + ((v.u >> 16) & 1u);  // round-to-nearest-even
  return (unsigned short)(r >> 16);
}

__device__ inline float4 bfu2_to_f4(uint2 u) {
  union { unsigned u; float f; } c;
  float4 r;
  c.u = u.x << 16;          r.x = c.f;
  c.u = u.x & 0xFFFF0000u;  r.y = c.f;
  c.u = u.y << 16;          r.z = c.f;
  c.u = u.y & 0xFFFF0000u;  r.w = c.f;
  return r;
}

__device__ inline float gelu_f(float v) {
  return 0.5f * v * (1.0f + erff(v * 0.70710678118654752440f));
}

// ---------- kernel 0: detect int32 vs int64 edge_index ----------
// int64 case: every odd 32-bit word (high word of a value < 40000) is 0.
// int32 case: odd words are random node ids -> virtually never all zero.
__global__ void detect_kernel(const unsigned* __restrict__ ei, int* __restrict__ flag) {
  __shared__ int nz;
  if (threadIdx.x == 0) nz = 0;
  __syncthreads();
  if (ei[2u * threadIdx.x + 1u] != 0u) nz = 1;  // benign race, all write 1
  __syncthreads();
  if (threadIdx.x == 0) *flag = nz;             // 1 -> int32, 0 -> int64
}

// ---------- kernel 1: scatter-add x[src] into summed[dst], count degree ----------
__global__ __launch_bounds__(256)
void scatter_kernel(const float* __restrict__ x, const void* __restrict__ ei,
                    const int* __restrict__ flag,
                    float* summed, float* __restrict__ deg) {
  unsigned gid = blockIdx.x * 256u + threadIdx.x;
  unsigned e = gid >> 5;         // edge id
  unsigned part = gid & 31u;     // which float4 of the 128-elem row
  if (e >= NE) return;
  int src, dst;
  if (*flag) {
    const int* p = (const int*)ei;
    src = p[e]; dst = p[NE + e];
  } else {
    const long long* p = (const long long*)ei;
    src = (int)p[e]; dst = (int)p[NE + e];
  }
  float4 v = *(const float4*)(x + (size_t)src * DD + part * 4u);
  float* b = summed + (size_t)dst * DD + part * 4u;
  unsafeAtomicAdd(b + 0, v.x);
  unsafeAtomicAdd(b + 1, v.y);
  unsafeAtomicAdd(b + 2, v.z);
  unsafeAtomicAdd(b + 3, v.w);
  if (part == 0) unsafeAtomicAdd(deg + dst, 1.0f);
}

// ---------- kernel 2: fused mean + SAGE linear + GELU + residual + LayerNorm ----------
// LDS: WT [256][WPAD] bf16 (rows 0..127 = Wl^T, 128..255 = Wr^T), A [SLOTS][256] bf16
// (A row = bf16(mean_nb row) || bf16(x row)). Thread t: slot = t>>5 (node within
// pass), jg = t&31 (4 output columns j0 = 4*jg).
__global__ __launch_bounds__(256, 2)
void fused_kernel(const float* __restrict__ xin,
                  const float* summed,            // aliases outp (read-before-write per node)
                  const float* __restrict__ deg,
                  const float* __restrict__ Wl,
                  const float* __restrict__ blv,
                  const float* __restrict__ Wr,
                  const float* __restrict__ gammav,
                  const float* __restrict__ betav,
                  float* outp) {
  extern __shared__ unsigned short smem[];
  unsigned short* WT = smem;                 // 256*WPAD bf16
  unsigned short* A  = smem + 256 * WPAD;    // SLOTS*256 bf16

  const int tid = threadIdx.x;

  // Stage W transposed into LDS as bf16: WT[k][j] = W2[j][k]
  for (int i = tid; i < 128 * 32; i += 256) {
    int j  = i >> 5;
    int kc = (i & 31) << 2;
    float4 wl = *(const float4*)(Wl + j * DD + kc);
    float4 wr = *(const float4*)(Wr + j * DD + kc);
    WT[(kc + 0) * WPAD + j] = f2bf(wl.x);
    WT[(kc + 1) * WPAD + j] = f2bf(wl.y);
    WT[(kc + 2) * WPAD + j] = f2bf(wl.z);
    WT[(kc + 3) * WPAD + j] = f2bf(wl.w);
    WT[(DD + kc + 0) * WPAD + j] = f2bf(wr.x);
    WT[(DD + kc + 1) * WPAD + j] = f2bf(wr.y);
    WT[(DD + kc + 2) * WPAD + j] = f2bf(wr.z);
    WT[(DD + kc + 3) * WPAD + j] = f2bf(wr.w);
  }

  const int slot = tid >> 5;
  const int jg   = tid & 31;
  const int j0   = jg << 2;
  unsigned short* ar = A + slot * 256;

  const int base = blockIdx.x * NPB;
  for (int pass = 0; pass < NPB / SLOTS; ++pass) {
    const int node = base + pass * SLOTS + slot;

    __syncthreads();  // previous pass done reading A (also fences W staging on pass 0)
    {
      float rdeg = 1.0f / fmaxf(deg[node], 1.0f);
      float4 sv = *(const float4*)(summed + (size_t)node * DD + j0);
      float4 xv = *(const float4*)(xin + (size_t)node * DD + j0);
      uint2 mp, xp;
      mp.x = (unsigned)f2bf(sv.x * rdeg) | ((unsigned)f2bf(sv.y * rdeg) << 16);
      mp.y = (unsigned)f2bf(sv.z * rdeg) | ((unsigned)f2bf(sv.w * rdeg) << 16);
      xp.x = (unsigned)f2bf(xv.x) | ((unsigned)f2bf(xv.y) << 16);
      xp.y = (unsigned)f2bf(xv.z) | ((unsigned)f2bf(xv.w) << 16);
      *(uint2*)(ar + j0) = mp;
      *(uint2*)(ar + DD + j0) = xp;
    }
    __syncthreads();

    float4 acc = *(const float4*)(blv + j0);
#pragma unroll 8
    for (int k = 0; k < 256; k += 4) {
      float4 av = bfu2_to_f4(*(const uint2*)(ar + k));
      float4 w0 = bfu2_to_f4(*(const uint2*)(WT + (k + 0) * WPAD + j0));
      float4 w1 = bfu2_to_f4(*(const uint2*)(WT + (k + 1) * WPAD + j0));
      float4 w2 = bfu2_to_f4(*(const uint2*)(WT + (k + 2) * WPAD + j0));
      float4 w3 = bfu2_to_f4(*(const uint2*)(WT + (k + 3) * WPAD + j0));
      acc.x += av.x * w0.x + av.y * w1.x + av.z * w2.x + av.w * w3.x;
      acc.y += av.x * w0.y + av.y * w1.y + av.z * w2.y + av.w * w3.y;
      acc.z += av.x * w0.z + av.y * w1.z + av.z * w2.z + av.w * w3.z;
      acc.w += av.x * w0.w + av.y * w1.w + av.z * w2.w + av.w * w3.w;
    }

    // epilogue: GELU + residual + LayerNorm over the 32-thread group
    float4 xv = *(const float4*)(xin + (size_t)node * DD + j0);
    float4 h;
    h.x = xv.x + gelu_f(acc.x);
    h.y = xv.y + gelu_f(acc.y);
    h.z = xv.z + gelu_f(acc.z);
    h.w = xv.w + gelu_f(acc.w);
    float s1 = h.x + h.y + h.z + h.w;
    float s2 = h.x * h.x + h.y * h.y + h.z * h.z + h.w * h.w;
#pragma unroll
    for (int off = 16; off > 0; off >>= 1) {
      s1 += __shfl_xor(s1, off, 32);
      s2 += __shfl_xor(s2, off, 32);
    }
    float mu   = s1 * (1.0f / DD);
    float var  = s2 * (1.0f / DD) - mu * mu;
    float rstd = rsqrtf(var + LN_EPS);
    float4 g = *(const float4*)(gammav + j0);
    float4 b = *(const float4*)(betav + j0);
    float4 r;
    r.x = (h.x - mu) * rstd * g.x + b.x;
    r.y = (h.y - mu) * rstd * g.y + b.y;
    r.z = (h.z - mu) * rstd * g.z + b.z;
    r.w = (h.w - mu) * rstd * g.w + b.w;
    *(float4*)(outp + (size_t)node * DD + j0) = r;
  }
}

extern "C" void kernel_launch(void* const* d_in, const int* in_sizes, int n_in,
                              void* d_out, int out_size, void* d_ws, size_t ws_size,
                              hipStream_t stream) {
  const float* x     = (const float*)d_in[0];
  const void*  ei    = d_in[1];
  const float* Wl    = (const float*)d_in[2];
  const float* bl    = (const float*)d_in[3];
  const float* Wr    = (const float*)d_in[4];
  const float* gamma = (const float*)d_in[5];
  const float* beta  = (const float*)d_in[6];
  float* out = (float*)d_out;

  float* deg = (float*)d_ws;            // NN floats
  int*   flag = (int*)d_ws + NN;        // 1 int

  // summed lives in d_out (exactly NN*DD fp32); zero it + deg each call
  hipMemsetAsync(d_out, 0, (size_t)NN * DD * sizeof(float), stream);
  hipMemsetAsync(d_ws, 0, (size_t)NN * sizeof(float), stream);

  detect_kernel<<<1, 256, 0, stream>>>((const unsigned*)ei, flag);

  scatter_kernel<<<(NE * 32) / 256, 256, 0, stream>>>(x, ei, flag, out, deg);

  size_t lds = (size_t)(256 * WPAD + SLOTS * 256) * sizeof(unsigned short);
  hipFuncSetAttribute((const void*)fused_kernel,
                      hipFuncAttributeMaxDynamicSharedMemorySize, (int)lds);
  fused_kernel<<<NN / NPB, 256, lds, stream>>>(x, out, deg, Wl, bl, Wr, gamma, beta, out);
}

// Round 2
// 329.756 us; speedup vs baseline: 3.7985x; 3.7985x over previous
//
#include <hip/hip_runtime.h>
#include <hip/hip_bf16.h>

#define NN 40000
#define NE 640000
#define DD 128
#define NPB 32      // nodes per block in fused kernel
#define SLOTS 8     // nodes processed per pass (256 threads / 32 per node)
#define WPAD 132    // padded LDS row stride (elements) to break bank conflicts
#define LN_EPS 1e-5f

// ---------- helpers ----------
__device__ inline unsigned short f2bf(float f) {
  union { float f; unsigned u; } v; v.f = f;
  unsigned r = v.u + 0x7FFFu + ((v.u >> 16) & 1u);  // round-to-nearest-even
  return (unsigned short)(r >> 16);
}

__device__ inline float4 bfu2_to_f4(uint2 u) {
  union { unsigned u; float f; } c;
  float4 r;
  c.u = u.x << 16;          r.x = c.f;
  c.u = u.x & 0xFFFF0000u;  r.y = c.f;
  c.u = u.y << 16;          r.z = c.f;
  c.u = u.y & 0xFFFF0000u;  r.w = c.f;
  return r;
}

__device__ inline float gelu_f(float v) {
  return 0.5f * v * (1.0f + erff(v * 0.70710678118654752440f));
}

// ---------- kernel 0: detect int32 vs int64 edge_index ----------
__global__ void detect_kernel(const unsigned* __restrict__ ei, int* __restrict__ flag) {
  __shared__ int nz;
  if (threadIdx.x == 0) nz = 0;
  __syncthreads();
  if (ei[2u * threadIdx.x + 1u] != 0u) nz = 1;  // benign race, all write 1
  __syncthreads();
  if (threadIdx.x == 0) *flag = nz;             // 1 -> int32, 0 -> int64
}

__device__ inline void load_edge(const void* ei, int use32, unsigned e, int& src, int& dst) {
  if (use32) {
    const int* p = (const int*)ei;
    src = p[e]; dst = p[NE + e];
  } else {
    const long long* p = (const long long*)ei;
    src = (int)p[e]; dst = (int)p[NE + e];
  }
}

// ---------- CSR path ----------
__global__ __launch_bounds__(256)
void hist_kernel(const void* __restrict__ ei, const int* __restrict__ flag,
                 int* __restrict__ deg) {
  unsigned e = blockIdx.x * 256u + threadIdx.x;
  if (e >= NE) return;
  int dst = *flag ? ((const int*)ei)[NE + e] : (int)((const long long*)ei)[NE + e];
  atomicAdd(&deg[dst], 1);
}

// single-block exclusive scan of deg[NN] -> offs, cursor
__global__ __launch_bounds__(1024)
void scan_kernel(const int* __restrict__ deg, int* __restrict__ offs,
                 int* __restrict__ cursor) {
  __shared__ int part[1024];
  const int t = threadIdx.x;
  const int CH = 40;               // 1024*40 >= 40000
  int local[CH];
  int base = t * CH, s = 0;
#pragma unroll
  for (int i = 0; i < CH; ++i) {
    int idx = base + i;
    int d = (idx < NN) ? deg[idx] : 0;
    local[i] = d; s += d;
  }
  part[t] = s;
  __syncthreads();
  for (int off = 1; off < 1024; off <<= 1) {
    int v = (t >= off) ? part[t - off] : 0;
    __syncthreads();
    part[t] += v;
    __syncthreads();
  }
  int run = (t > 0) ? part[t - 1] : 0;
#pragma unroll
  for (int i = 0; i < CH; ++i) {
    int idx = base + i;
    if (idx < NN) { offs[idx] = run; cursor[idx] = run; run += local[i]; }
  }
}

__global__ __launch_bounds__(256)
void fill_kernel(const void* __restrict__ ei, const int* __restrict__ flag,
                 int* __restrict__ cursor, int* __restrict__ csr) {
  unsigned e = blockIdx.x * 256u + threadIdx.x;
  if (e >= NE) return;
  int src, dst;
  load_edge(ei, *flag, e, src, dst);
  int pos = atomicAdd(&cursor[dst], 1);
  csr[pos] = src;
}

// one wave64 per node: mean over neighbor rows (coalesced 512B per neighbor)
__global__ __launch_bounds__(256)
void gather_kernel(const float* __restrict__ x, const int* __restrict__ offs,
                   const int* __restrict__ deg, const int* __restrict__ csr,
                   float* __restrict__ mean) {
  const int wave = threadIdx.x >> 6;
  const int lane = threadIdx.x & 63;
  const int node = blockIdx.x * 4 + wave;
  const int beg = offs[node];
  const int d = deg[node];
  float2 acc = {0.f, 0.f};
  const float* xb = x + lane * 2;
  for (int i = 0; i < d; ++i) {
    int s = csr[beg + i];
    float2 v = *(const float2*)(xb + (size_t)s * DD);
    acc.x += v.x; acc.y += v.y;
  }
  float r = 1.0f / fmaxf((float)d, 1.0f);
  float2 m = {acc.x * r, acc.y * r};
  *(float2*)(mean + (size_t)node * DD + lane * 2) = m;
}

// ---------- fallback (atomic scatter, as R0) ----------
__global__ __launch_bounds__(256)
void scatter_kernel(const float* __restrict__ x, const void* __restrict__ ei,
                    const int* __restrict__ flag,
                    float* summed, float* __restrict__ deg) {
  unsigned gid = blockIdx.x * 256u + threadIdx.x;
  unsigned e = gid >> 5;
  unsigned part = gid & 31u;
  if (e >= NE) return;
  int src, dst;
  load_edge(ei, *flag, e, src, dst);
  float4 v = *(const float4*)(x + (size_t)src * DD + part * 4u);
  float* b = summed + (size_t)dst * DD + part * 4u;
  unsafeAtomicAdd(b + 0, v.x);
  unsafeAtomicAdd(b + 1, v.y);
  unsafeAtomicAdd(b + 2, v.z);
  unsafeAtomicAdd(b + 3, v.w);
  if (part == 0) unsafeAtomicAdd(deg + dst, 1.0f);
}

// ---------- fused: (optional mean-div) + SAGE linear + GELU + residual + LN ----------
__global__ __launch_bounds__(256, 2)
void fused_kernel(const float* __restrict__ xin,
                  const float* agg,               // aliases outp (read-before-write per node)
                  const float* __restrict__ degf, // used only when divide=1
                  int divide,
                  const float* __restrict__ Wl,
                  const float* __restrict__ blv,
                  const float* __restrict__ Wr,
                  const float* __restrict__ gammav,
                  const float* __restrict__ betav,
                  float* outp) {
  extern __shared__ unsigned short smem[];
  unsigned short* WT = smem;                 // 256*WPAD bf16
  unsigned short* A  = smem + 256 * WPAD;    // SLOTS*256 bf16

  const int tid = threadIdx.x;

  for (int i = tid; i < 128 * 32; i += 256) {
    int j  = i >> 5;
    int kc = (i & 31) << 2;
    float4 wl = *(const float4*)(Wl + j * DD + kc);
    float4 wr = *(const float4*)(Wr + j * DD + kc);
    WT[(kc + 0) * WPAD + j] = f2bf(wl.x);
    WT[(kc + 1) * WPAD + j] = f2bf(wl.y);
    WT[(kc + 2) * WPAD + j] = f2bf(wl.z);
    WT[(kc + 3) * WPAD + j] = f2bf(wl.w);
    WT[(DD + kc + 0) * WPAD + j] = f2bf(wr.x);
    WT[(DD + kc + 1) * WPAD + j] = f2bf(wr.y);
    WT[(DD + kc + 2) * WPAD + j] = f2bf(wr.z);
    WT[(DD + kc + 3) * WPAD + j] = f2bf(wr.w);
  }

  const int slot = tid >> 5;
  const int jg   = tid & 31;
  const int j0   = jg << 2;
  unsigned short* ar = A + slot * 256;

  const int base = blockIdx.x * NPB;
  for (int pass = 0; pass < NPB / SLOTS; ++pass) {
    const int node = base + pass * SLOTS + slot;

    __syncthreads();
    {
      float rdeg = divide ? (1.0f / fmaxf(degf[node], 1.0f)) : 1.0f;
      float4 sv = *(const float4*)(agg + (size_t)node * DD + j0);
      float4 xv = *(const float4*)(xin + (size_t)node * DD + j0);
      uint2 mp, xp;
      mp.x = (unsigned)f2bf(sv.x * rdeg) | ((unsigned)f2bf(sv.y * rdeg) << 16);
      mp.y = (unsigned)f2bf(sv.z * rdeg) | ((unsigned)f2bf(sv.w * rdeg) << 16);
      xp.x = (unsigned)f2bf(xv.x) | ((unsigned)f2bf(xv.y) << 16);
      xp.y = (unsigned)f2bf(xv.z) | ((unsigned)f2bf(xv.w) << 16);
      *(uint2*)(ar + j0) = mp;
      *(uint2*)(ar + DD + j0) = xp;
    }
    __syncthreads();

    float4 acc = *(const float4*)(blv + j0);
#pragma unroll 8
    for (int k = 0; k < 256; k += 4) {
      float4 av = bfu2_to_f4(*(const uint2*)(ar + k));
      float4 w0 = bfu2_to_f4(*(const uint2*)(WT + (k + 0) * WPAD + j0));
      float4 w1 = bfu2_to_f4(*(const uint2*)(WT + (k + 1) * WPAD + j0));
      float4 w2 = bfu2_to_f4(*(const uint2*)(WT + (k + 2) * WPAD + j0));
      float4 w3 = bfu2_to_f4(*(const uint2*)(WT + (k + 3) * WPAD + j0));
      acc.x += av.x * w0.x + av.y * w1.x + av.z * w2.x + av.w * w3.x;
      acc.y += av.x * w0.y + av.y * w1.y + av.z * w2.y + av.w * w3.y;
      acc.z += av.x * w0.z + av.y * w1.z + av.z * w2.z + av.w * w3.z;
      acc.w += av.x * w0.w + av.y * w1.w + av.z * w2.w + av.w * w3.w;
    }

    float4 xv = *(const float4*)(xin + (size_t)node * DD + j0);
    float4 h;
    h.x = xv.x + gelu_f(acc.x);
    h.y = xv.y + gelu_f(acc.y);
    h.z = xv.z + gelu_f(acc.z);
    h.w = xv.w + gelu_f(acc.w);
    float s1 = h.x + h.y + h.z + h.w;
    float s2 = h.x * h.x + h.y * h.y + h.z * h.z + h.w * h.w;
#pragma unroll
    for (int off = 16; off > 0; off >>= 1) {
      s1 += __shfl_xor(s1, off, 32);
      s2 += __shfl_xor(s2, off, 32);
    }
    float mu   = s1 * (1.0f / DD);
    float var  = s2 * (1.0f / DD) - mu * mu;
    float rstd = rsqrtf(var + LN_EPS);
    float4 g = *(const float4*)(gammav + j0);
    float4 b = *(const float4*)(betav + j0);
    float4 r;
    r.x = (h.x - mu) * rstd * g.x + b.x;
    r.y = (h.y - mu) * rstd * g.y + b.y;
    r.z = (h.z - mu) * rstd * g.z + b.z;
    r.w = (h.w - mu) * rstd * g.w + b.w;
    *(float4*)(outp + (size_t)node * DD + j0) = r;
  }
}

extern "C" void kernel_launch(void* const* d_in, const int* in_sizes, int n_in,
                              void* d_out, int out_size, void* d_ws, size_t ws_size,
                              hipStream_t stream) {
  const float* x     = (const float*)d_in[0];
  const void*  ei    = d_in[1];
  const float* Wl    = (const float*)d_in[2];
  const float* bl    = (const float*)d_in[3];
  const float* Wr    = (const float*)d_in[4];
  const float* gamma = (const float*)d_in[5];
  const float* beta  = (const float*)d_in[6];
  float* out = (float*)d_out;

  size_t lds = (size_t)(256 * WPAD + SLOTS * 256) * sizeof(unsigned short);
  hipFuncSetAttribute((const void*)fused_kernel,
                      hipFuncAttributeMaxDynamicSharedMemorySize, (int)lds);

  const size_t csr_need = (size_t)(3 * NN + NE + 1) * sizeof(int);

  if (ws_size >= csr_need) {
    // ---- CSR pull path ----
    int* deg    = (int*)d_ws;            // NN
    int* offs   = deg + NN;              // NN
    int* cursor = offs + NN;             // NN
    int* csr    = cursor + NN;           // NE
    int* flag   = csr + NE;              // 1

    hipMemsetAsync(deg, 0, (size_t)NN * sizeof(int), stream);
    detect_kernel<<<1, 256, 0, stream>>>((const unsigned*)ei, flag);
    hist_kernel<<<(NE + 255) / 256, 256, 0, stream>>>(ei, flag, deg);
    scan_kernel<<<1, 1024, 0, stream>>>(deg, offs, cursor);
    fill_kernel<<<(NE + 255) / 256, 256, 0, stream>>>(ei, flag, cursor, csr);
    gather_kernel<<<NN / 4, 256, 0, stream>>>(x, offs, deg, csr, out);
    fused_kernel<<<NN / NPB, 256, lds, stream>>>(x, out, nullptr, 0,
                                                 Wl, bl, Wr, gamma, beta, out);
  } else {
    // ---- fallback: atomic scatter path (R0) ----
    float* degf = (float*)d_ws;          // NN
    int*   flag = (int*)d_ws + NN;       // 1

    hipMemsetAsync(d_out, 0, (size_t)NN * DD * sizeof(float), stream);
    hipMemsetAsync(d_ws, 0, (size_t)NN * sizeof(float), stream);
    detect_kernel<<<1, 256, 0, stream>>>((const unsigned*)ei, flag);
    scatter_kernel<<<(NE * 32) / 256, 256, 0, stream>>>(x, ei, flag, out, degf);
    fused_kernel<<<NN / NPB, 256, lds, stream>>>(x, out, degf, 1,
                                                 Wl, bl, Wr, gamma, beta, out);
  }
}

// Round 3
// 229.077 us; speedup vs baseline: 5.4679x; 1.4395x over previous
//
#include <hip/hip_runtime.h>
#include <hip/hip_bf16.h>

#define NN 40000
#define NE 640000
#define DD 128
#define LN_EPS 1e-5f
#define BTSTRIDE 264   // bf16 elements per BT row (256 + 8 pad)

typedef __attribute__((ext_vector_type(8))) short short8;
typedef __attribute__((ext_vector_type(4))) float f32x4;

// ---------- helpers ----------
__device__ inline unsigned short f2bf(float f) {
  union { float f; unsigned u; } v; v.f = f;
  unsigned r = v.u + 0x7FFFu + ((v.u >> 16) & 1u);  // round-to-nearest-even
  return (unsigned short)(r >> 16);
}

__device__ inline float gelu_f(float v) {
  return 0.5f * v * (1.0f + erff(v * 0.70710678118654752440f));
}

// ---------- kernel 0: detect int32 vs int64 edge_index ----------
__global__ void detect_kernel(const unsigned* __restrict__ ei, int* __restrict__ flag) {
  __shared__ int nz;
  if (threadIdx.x == 0) nz = 0;
  __syncthreads();
  if (ei[2u * threadIdx.x + 1u] != 0u) nz = 1;  // benign race, all write 1
  __syncthreads();
  if (threadIdx.x == 0) *flag = nz;             // 1 -> int32, 0 -> int64
}

__device__ inline void load_edge(const void* ei, int use32, unsigned e, int& src, int& dst) {
  if (use32) {
    const int* p = (const int*)ei;
    src = p[e]; dst = p[NE + e];
  } else {
    const long long* p = (const long long*)ei;
    src = (int)p[e]; dst = (int)p[NE + e];
  }
}

// ---------- CSR build ----------
__global__ __launch_bounds__(256)
void hist_kernel(const void* __restrict__ ei, const int* __restrict__ flag,
                 int* __restrict__ deg) {
  unsigned e = blockIdx.x * 256u + threadIdx.x;
  if (e >= NE) return;
  int dst = *flag ? ((const int*)ei)[NE + e] : (int)((const long long*)ei)[NE + e];
  atomicAdd(&deg[dst], 1);
}

__global__ __launch_bounds__(1024)
void scan_kernel(const int* __restrict__ deg, int* __restrict__ offs,
                 int* __restrict__ cursor) {
  __shared__ int part[1024];
  const int t = threadIdx.x;
  const int CH = 40;               // 1024*40 >= 40000
  int local[CH];
  int base = t * CH, s = 0;
#pragma unroll
  for (int i = 0; i < CH; ++i) {
    int idx = base + i;
    int d = (idx < NN) ? deg[idx] : 0;
    local[i] = d; s += d;
  }
  part[t] = s;
  __syncthreads();
  for (int off = 1; off < 1024; off <<= 1) {
    int v = (t >= off) ? part[t - off] : 0;
    __syncthreads();
    part[t] += v;
    __syncthreads();
  }
  int run = (t > 0) ? part[t - 1] : 0;
#pragma unroll
  for (int i = 0; i < CH; ++i) {
    int idx = base + i;
    if (idx < NN) { offs[idx] = run; cursor[idx] = run; run += local[i]; }
  }
}

__global__ __launch_bounds__(256)
void fill_kernel(const void* __restrict__ ei, const int* __restrict__ flag,
                 int* __restrict__ cursor, int* __restrict__ csr) {
  unsigned e = blockIdx.x * 256u + threadIdx.x;
  if (e >= NE) return;
  int src, dst;
  load_edge(ei, *flag, e, src, dst);
  int pos = atomicAdd(&cursor[dst], 1);
  csr[pos] = src;
}

// ---------- gather: wave per node -> A = [bf16(mean) | bf16(x)]  [NN][256] ----------
__global__ __launch_bounds__(256)
void gatherA_kernel(const float* __restrict__ x, const int* __restrict__ offs,
                    const int* __restrict__ deg, const int* __restrict__ csr,
                    unsigned short* __restrict__ A) {
  const int wave = threadIdx.x >> 6;
  const int lane = threadIdx.x & 63;
  const int node = blockIdx.x * 4 + wave;
  const int beg = offs[node];
  const int d = deg[node];
  float2 acc = {0.f, 0.f};
  const float* xb = x + lane * 2;
  for (int i = 0; i < d; ++i) {
    int s = csr[beg + i];
    float2 v = *(const float2*)(xb + (size_t)s * DD);
    acc.x += v.x; acc.y += v.y;
  }
  float r = 1.0f / fmaxf((float)d, 1.0f);
  ushort2 m; m.x = f2bf(acc.x * r); m.y = f2bf(acc.y * r);
  float2 xv = *(const float2*)(x + (size_t)node * DD + lane * 2);
  ushort2 xo; xo.x = f2bf(xv.x); xo.y = f2bf(xv.y);
  *(ushort2*)(A + (size_t)node * 256 + lane * 2) = m;
  *(ushort2*)(A + (size_t)node * 256 + DD + lane * 2) = xo;
}

// ---------- fallback: atomic scatter + in-place convert to A ----------
__global__ __launch_bounds__(256)
void scatter_kernel(const float* __restrict__ x, const void* __restrict__ ei,
                    const int* __restrict__ flag,
                    float* summed, float* __restrict__ deg) {
  unsigned gid = blockIdx.x * 256u + threadIdx.x;
  unsigned e = gid >> 5;
  unsigned part = gid & 31u;
  if (e >= NE) return;
  int src, dst;
  load_edge(ei, *flag, e, src, dst);
  float4 v = *(const float4*)(x + (size_t)src * DD + part * 4u);
  float* b = summed + (size_t)dst * DD + part * 4u;
  unsafeAtomicAdd(b + 0, v.x);
  unsafeAtomicAdd(b + 1, v.y);
  unsafeAtomicAdd(b + 2, v.z);
  unsafeAtomicAdd(b + 3, v.w);
  if (part == 0) unsafeAtomicAdd(deg + dst, 1.0f);
}

__global__ __launch_bounds__(256)
void convertA_kernel(const float* __restrict__ x, const float* __restrict__ degf,
                     float* sum /* aliases A */, unsigned short* A) {
  const int wave = threadIdx.x >> 6;
  const int lane = threadIdx.x & 63;
  const int node = blockIdx.x * 4 + wave;
  float2 sv = *(const float2*)(sum + (size_t)node * DD + lane * 2);
  float r = 1.0f / fmaxf(degf[node], 1.0f);
  float2 xv = *(const float2*)(x + (size_t)node * DD + lane * 2);
  asm volatile("" ::: "memory");  // order loads before aliased stores
  ushort2 m; m.x = f2bf(sv.x * r); m.y = f2bf(sv.y * r);
  ushort2 xo; xo.x = f2bf(xv.x); xo.y = f2bf(xv.y);
  *(ushort2*)(A + (size_t)node * 256 + lane * 2) = m;
  *(ushort2*)(A + (size_t)node * 256 + DD + lane * 2) = xo;
}

// ---------- MFMA fused: A[128 rows]x[256] @ BT^T + bias -> GELU -> +x -> LN ----------
// 4 waves, wave w owns rows [w*32, w*32+32) of the block's 128 rows.
// BT[j][k] = W2[j][k] bf16 in LDS, stride 264 (even 16B-slot spread).
__global__ __launch_bounds__(256, 2)
void mfma_fused_kernel(const unsigned short* __restrict__ A,
                       const float* __restrict__ xin,
                       const float* __restrict__ Wl,
                       const float* __restrict__ blv,
                       const float* __restrict__ Wr,
                       const float* __restrict__ gammav,
                       const float* __restrict__ betav,
                       float* __restrict__ outp) {
  extern __shared__ unsigned short BT[];  // [128][BTSTRIDE]
  const int tid = threadIdx.x;

  // stage W^T (stacked [Wl|Wr] along k) as bf16
  for (int i = tid; i < 128 * 32; i += 256) {
    int j  = i >> 5;
    int kc = (i & 31) << 2;
    float4 wl = *(const float4*)(Wl + j * DD + kc);
    float4 wr = *(const float4*)(Wr + j * DD + kc);
    unsigned short* p = BT + j * BTSTRIDE + kc;
    p[0] = f2bf(wl.x); p[1] = f2bf(wl.y); p[2] = f2bf(wl.z); p[3] = f2bf(wl.w);
    p[DD + 0] = f2bf(wr.x); p[DD + 1] = f2bf(wr.y);
    p[DD + 2] = f2bf(wr.z); p[DD + 3] = f2bf(wr.w);
  }
  __syncthreads();

  const int wv = tid >> 6;
  const int l  = tid & 63;
  const int row0 = blockIdx.x * 128 + wv * 32;
  const int ar = l & 15;     // row/col-within-tile index
  const int kg = l >> 4;     // k-group (8 contiguous k per group)

  f32x4 acc[2][8];
#pragma unroll
  for (int rt = 0; rt < 2; ++rt)
#pragma unroll
    for (int ct = 0; ct < 8; ++ct)
      acc[rt][ct] = (f32x4){0.f, 0.f, 0.f, 0.f};

  const int r0 = min(row0 + ar, NN - 1);
  const int r1 = min(row0 + 16 + ar, NN - 1);

#pragma unroll
  for (int ks = 0; ks < 8; ++ks) {
    const int kb = ks * 32 + kg * 8;
    short8 a0 = *(const short8*)(A + (size_t)r0 * 256 + kb);
    short8 a1 = *(const short8*)(A + (size_t)r1 * 256 + kb);
#pragma unroll
    for (int ct = 0; ct < 8; ++ct) {
      short8 b = *(const short8*)(BT + (ct * 16 + ar) * BTSTRIDE + kb);
      acc[0][ct] = __builtin_amdgcn_mfma_f32_16x16x32_bf16(a0, b, acc[0][ct], 0, 0, 0);
      acc[1][ct] = __builtin_amdgcn_mfma_f32_16x16x32_bf16(a1, b, acc[1][ct], 0, 0, 0);
    }
  }

  // epilogue: C/D layout col = ar, row = kg*4 + r (within 16x16 tile)
  float blr[8], gr[8], br[8];
#pragma unroll
  for (int ct = 0; ct < 8; ++ct) {
    blr[ct] = blv[ct * 16 + ar];
    gr[ct]  = gammav[ct * 16 + ar];
    br[ct]  = betav[ct * 16 + ar];
  }

#pragma unroll
  for (int rt = 0; rt < 2; ++rt) {
#pragma unroll
    for (int r = 0; r < 4; ++r) {
      const int row = row0 + rt * 16 + kg * 4 + r;
      if (row < NN) {
        float h[8];
        float s1 = 0.f, s2 = 0.f;
#pragma unroll
        for (int ct = 0; ct < 8; ++ct) {
          float v = acc[rt][ct][r] + blr[ct];
          float hh = xin[(size_t)row * DD + ct * 16 + ar] + gelu_f(v);
          h[ct] = hh; s1 += hh; s2 += hh * hh;
        }
#pragma unroll
        for (int off = 8; off > 0; off >>= 1) {
          s1 += __shfl_xor(s1, off);
          s2 += __shfl_xor(s2, off);
        }
        float mu   = s1 * (1.0f / DD);
        float var  = s2 * (1.0f / DD) - mu * mu;
        float rstd = rsqrtf(var + LN_EPS);
#pragma unroll
        for (int ct = 0; ct < 8; ++ct)
          outp[(size_t)row * DD + ct * 16 + ar] = (h[ct] - mu) * rstd * gr[ct] + br[ct];
      }
    }
  }
}

extern "C" void kernel_launch(void* const* d_in, const int* in_sizes, int n_in,
                              void* d_out, int out_size, void* d_ws, size_t ws_size,
                              hipStream_t stream) {
  const float* x     = (const float*)d_in[0];
  const void*  ei    = d_in[1];
  const float* Wl    = (const float*)d_in[2];
  const float* bl    = (const float*)d_in[3];
  const float* Wr    = (const float*)d_in[4];
  const float* gamma = (const float*)d_in[5];
  const float* beta  = (const float*)d_in[6];
  float* out = (float*)d_out;
  unsigned short* A = (unsigned short*)d_out;  // bf16 [NN][256], same bytes as out

  size_t lds = (size_t)128 * BTSTRIDE * sizeof(unsigned short);
  hipFuncSetAttribute((const void*)mfma_fused_kernel,
                      hipFuncAttributeMaxDynamicSharedMemorySize, (int)lds);

  const size_t csr_need = (size_t)(3 * NN + NE + 1) * sizeof(int);
  const int mfma_blocks = (NN + 127) / 128;

  if (ws_size >= csr_need) {
    // ---- CSR pull path ----
    int* deg    = (int*)d_ws;            // NN
    int* offs   = deg + NN;              // NN
    int* cursor = offs + NN;             // NN
    int* csr    = cursor + NN;           // NE
    int* flag   = csr + NE;              // 1

    hipMemsetAsync(deg, 0, (size_t)NN * sizeof(int), stream);
    detect_kernel<<<1, 256, 0, stream>>>((const unsigned*)ei, flag);
    hist_kernel<<<(NE + 255) / 256, 256, 0, stream>>>(ei, flag, deg);
    scan_kernel<<<1, 1024, 0, stream>>>(deg, offs, cursor);
    fill_kernel<<<(NE + 255) / 256, 256, 0, stream>>>(ei, flag, cursor, csr);
    gatherA_kernel<<<NN / 4, 256, 0, stream>>>(x, offs, deg, csr, A);
    mfma_fused_kernel<<<mfma_blocks, 256, lds, stream>>>(A, x, Wl, bl, Wr,
                                                         gamma, beta, out);
  } else {
    // ---- fallback: atomic scatter path ----
    float* degf = (float*)d_ws;          // NN
    int*   flag = (int*)d_ws + NN;       // 1

    hipMemsetAsync(d_out, 0, (size_t)NN * DD * sizeof(float), stream);
    hipMemsetAsync(d_ws, 0, (size_t)NN * sizeof(float), stream);
    detect_kernel<<<1, 256, 0, stream>>>((const unsigned*)ei, flag);
    scatter_kernel<<<(NE * 32) / 256, 256, 0, stream>>>(x, ei, flag, out, degf);
    convertA_kernel<<<NN / 4, 256, 0, stream>>>(x, degf, out, A);
    mfma_fused_kernel<<<mfma_blocks, 256, lds, stream>>>(A, x, Wl, bl, Wr,
                                                         gamma, beta, out);
  }
}

// Round 4
// 200.265 us; speedup vs baseline: 6.2546x; 1.1439x over previous
//
#include <hip/hip_runtime.h>
#include <hip/hip_bf16.h>

#define NN 40000
#define NE 640000
#define DD 128
#define LN_EPS 1e-5f
#define BTSTRIDE 264   // bf16 elements per BT row (256 + 8 pad)

typedef __attribute__((ext_vector_type(8))) short short8;
typedef __attribute__((ext_vector_type(4))) unsigned short ushort4v;
typedef __attribute__((ext_vector_type(4))) float f32x4;

// ---------- helpers ----------
__device__ inline unsigned short f2bf(float f) {
  union { float f; unsigned u; } v; v.f = f;
  unsigned r = v.u + 0x7FFFu + ((v.u >> 16) & 1u);  // round-to-nearest-even
  return (unsigned short)(r >> 16);
}

__device__ inline float bf2f(unsigned short b) {
  union { unsigned u; float f; } c;
  c.u = ((unsigned)b) << 16;
  return c.f;
}

__device__ inline float gelu_f(float v) {
  return 0.5f * v * (1.0f + erff(v * 0.70710678118654752440f));
}

// ---------- kernel 0: detect int32 vs int64 edge_index ----------
__global__ void detect_kernel(const unsigned* __restrict__ ei, int* __restrict__ flag) {
  __shared__ int nz;
  if (threadIdx.x == 0) nz = 0;
  __syncthreads();
  if (ei[2u * threadIdx.x + 1u] != 0u) nz = 1;  // benign race, all write 1
  __syncthreads();
  if (threadIdx.x == 0) *flag = nz;             // 1 -> int32, 0 -> int64
}

__device__ inline void load_edge(const void* ei, int use32, unsigned e, int& src, int& dst) {
  if (use32) {
    const int* p = (const int*)ei;
    src = p[e]; dst = p[NE + e];
  } else {
    const long long* p = (const long long*)ei;
    src = (int)p[e]; dst = (int)p[NE + e];
  }
}

// ---------- CSR build ----------
__global__ __launch_bounds__(256)
void hist_kernel(const void* __restrict__ ei, const int* __restrict__ flag,
                 int* __restrict__ deg) {
  unsigned e = blockIdx.x * 256u + threadIdx.x;
  if (e >= NE) return;
  int dst = *flag ? ((const int*)ei)[NE + e] : (int)((const long long*)ei)[NE + e];
  atomicAdd(&deg[dst], 1);
}

__global__ __launch_bounds__(1024)
void scan_kernel(const int* __restrict__ deg, int* __restrict__ offs,
                 int* __restrict__ cursor) {
  __shared__ int part[1024];
  const int t = threadIdx.x;
  const int CH = 40;               // 1024*40 >= 40000
  int local[CH];
  int base = t * CH, s = 0;
#pragma unroll
  for (int i = 0; i < CH; ++i) {
    int idx = base + i;
    int d = (idx < NN) ? deg[idx] : 0;
    local[i] = d; s += d;
  }
  part[t] = s;
  __syncthreads();
  for (int off = 1; off < 1024; off <<= 1) {
    int v = (t >= off) ? part[t - off] : 0;
    __syncthreads();
    part[t] += v;
    __syncthreads();
  }
  int run = (t > 0) ? part[t - 1] : 0;
#pragma unroll
  for (int i = 0; i < CH; ++i) {
    int idx = base + i;
    if (idx < NN) { offs[idx] = run; cursor[idx] = run; run += local[i]; }
  }
}

__global__ __launch_bounds__(256)
void fill_kernel(const void* __restrict__ ei, const int* __restrict__ flag,
                 int* __restrict__ cursor, int* __restrict__ csr) {
  unsigned e = blockIdx.x * 256u + threadIdx.x;
  if (e >= NE) return;
  int src, dst;
  load_edge(ei, *flag, e, src, dst);
  int pos = atomicAdd(&cursor[dst], 1);
  csr[pos] = src;
}

// ---------- x -> bf16 into A's x-half (A[node][128..256]) ----------
__global__ __launch_bounds__(256)
void xtobf_kernel(const float* __restrict__ x, unsigned short* __restrict__ A) {
  size_t gid = (size_t)blockIdx.x * 256 + threadIdx.x;
  size_t e0 = gid * 8;                  // 8 elements per thread
  int node = (int)(e0 >> 7);
  int k = (int)(e0 & 127);
  float4 a = *(const float4*)(x + e0);
  float4 b = *(const float4*)(x + e0 + 4);
  short8 o;
  o[0] = (short)f2bf(a.x); o[1] = (short)f2bf(a.y);
  o[2] = (short)f2bf(a.z); o[3] = (short)f2bf(a.w);
  o[4] = (short)f2bf(b.x); o[5] = (short)f2bf(b.y);
  o[6] = (short)f2bf(b.z); o[7] = (short)f2bf(b.w);
  *(short8*)(A + (size_t)node * 256 + 128 + k) = o;
}

// ---------- gather: 16 lanes per node, bf16 rows from A's x-half ----------
__global__ __launch_bounds__(256)
void gather16_kernel(const int* __restrict__ offs, const int* __restrict__ deg,
                     const int* __restrict__ csr, unsigned short* __restrict__ A) {
  const int grp = threadIdx.x >> 4;
  const int l16 = threadIdx.x & 15;
  const int node = blockIdx.x * 16 + grp;
  const int beg = offs[node];
  const int d = deg[node];
  float acc[8];
#pragma unroll
  for (int j = 0; j < 8; ++j) acc[j] = 0.f;
  const unsigned short* base = A + 128 + l16 * 8;  // x-half
  int idx = (d > 0) ? csr[beg] : 0;
  for (int i = 0; i < d; ++i) {
    int nidx = (i + 1 < d) ? csr[beg + i + 1] : 0;
    short8 v = *(const short8*)(base + (size_t)idx * 256);
#pragma unroll
    for (int j = 0; j < 8; ++j) acc[j] += bf2f((unsigned short)v[j]);
    idx = nidx;
  }
  float r = 1.0f / fmaxf((float)d, 1.0f);
  short8 o;
#pragma unroll
  for (int j = 0; j < 8; ++j) o[j] = (short)f2bf(acc[j] * r);
  *(short8*)(A + (size_t)node * 256 + l16 * 8) = o;
}

// ---------- fallback: atomic scatter + in-place convert to A ----------
__global__ __launch_bounds__(256)
void scatter_kernel(const float* __restrict__ x, const void* __restrict__ ei,
                    const int* __restrict__ flag,
                    float* summed, float* __restrict__ deg) {
  unsigned gid = blockIdx.x * 256u + threadIdx.x;
  unsigned e = gid >> 5;
  unsigned part = gid & 31u;
  if (e >= NE) return;
  int src, dst;
  load_edge(ei, *flag, e, src, dst);
  float4 v = *(const float4*)(x + (size_t)src * DD + part * 4u);
  float* b = summed + (size_t)dst * DD + part * 4u;
  unsafeAtomicAdd(b + 0, v.x);
  unsafeAtomicAdd(b + 1, v.y);
  unsafeAtomicAdd(b + 2, v.z);
  unsafeAtomicAdd(b + 3, v.w);
  if (part == 0) unsafeAtomicAdd(deg + dst, 1.0f);
}

__global__ __launch_bounds__(256)
void convertA_kernel(const float* __restrict__ x, const float* __restrict__ degf,
                     float* sum /* aliases A */, unsigned short* A) {
  const int wave = threadIdx.x >> 6;
  const int lane = threadIdx.x & 63;
  const int node = blockIdx.x * 4 + wave;
  float2 sv = *(const float2*)(sum + (size_t)node * DD + lane * 2);
  float r = 1.0f / fmaxf(degf[node], 1.0f);
  float2 xv = *(const float2*)(x + (size_t)node * DD + lane * 2);
  asm volatile("" ::: "memory");  // order loads before aliased stores
  ushort2 m; m.x = f2bf(sv.x * r); m.y = f2bf(sv.y * r);
  ushort2 xo; xo.x = f2bf(xv.x); xo.y = f2bf(xv.y);
  *(ushort2*)(A + (size_t)node * 256 + lane * 2) = m;
  *(ushort2*)(A + (size_t)node * 256 + DD + lane * 2) = xo;
}

// ---------- MFMA fused: A[128 rows]x[256] @ BT^T + bias -> GELU -> +x -> LN ----------
__global__ __launch_bounds__(256, 2)
void mfma_fused_kernel(const unsigned short* __restrict__ A,
                       const float* __restrict__ xin,
                       const float* __restrict__ Wl,
                       const float* __restrict__ blv,
                       const float* __restrict__ Wr,
                       const float* __restrict__ gammav,
                       const float* __restrict__ betav,
                       float* __restrict__ outp) {
  extern __shared__ unsigned short BT[];  // [128][BTSTRIDE]
  const int tid = threadIdx.x;

  // stage W^T (stacked [Wl|Wr] along k) as bf16, vectorized ds_write_b64
  for (int i = tid; i < 128 * 32; i += 256) {
    int j  = i >> 5;
    int kc = (i & 31) << 2;
    float4 wl = *(const float4*)(Wl + j * DD + kc);
    float4 wr = *(const float4*)(Wr + j * DD + kc);
    ushort4v pl = {f2bf(wl.x), f2bf(wl.y), f2bf(wl.z), f2bf(wl.w)};
    ushort4v pr = {f2bf(wr.x), f2bf(wr.y), f2bf(wr.z), f2bf(wr.w)};
    *(ushort4v*)(BT + j * BTSTRIDE + kc) = pl;
    *(ushort4v*)(BT + j * BTSTRIDE + DD + kc) = pr;
  }
  __syncthreads();

  const int wv = tid >> 6;
  const int l  = tid & 63;
  const int row0 = blockIdx.x * 128 + wv * 32;
  const int ar = l & 15;     // row/col-within-tile index
  const int kg = l >> 4;     // k-group (8 contiguous k per group)

  f32x4 acc[2][8];
#pragma unroll
  for (int rt = 0; rt < 2; ++rt)
#pragma unroll
    for (int ct = 0; ct < 8; ++ct)
      acc[rt][ct] = (f32x4){0.f, 0.f, 0.f, 0.f};

  const int r0 = min(row0 + ar, NN - 1);
  const int r1 = min(row0 + 16 + ar, NN - 1);

#pragma unroll
  for (int ks = 0; ks < 8; ++ks) {
    const int kb = ks * 32 + kg * 8;
    short8 a0 = *(const short8*)(A + (size_t)r0 * 256 + kb);
    short8 a1 = *(const short8*)(A + (size_t)r1 * 256 + kb);
#pragma unroll
    for (int ct = 0; ct < 8; ++ct) {
      short8 b = *(const short8*)(BT + (ct * 16 + ar) * BTSTRIDE + kb);
      acc[0][ct] = __builtin_amdgcn_mfma_f32_16x16x32_bf16(a0, b, acc[0][ct], 0, 0, 0);
      acc[1][ct] = __builtin_amdgcn_mfma_f32_16x16x32_bf16(a1, b, acc[1][ct], 0, 0, 0);
    }
  }

  float blr[8], gr[8], br[8];
#pragma unroll
  for (int ct = 0; ct < 8; ++ct) {
    blr[ct] = blv[ct * 16 + ar];
    gr[ct]  = gammav[ct * 16 + ar];
    br[ct]  = betav[ct * 16 + ar];
  }

#pragma unroll
  for (int rt = 0; rt < 2; ++rt) {
#pragma unroll
    for (int r = 0; r < 4; ++r) {
      const int row = row0 + rt * 16 + kg * 4 + r;
      if (row < NN) {
        float h[8];
        float s1 = 0.f, s2 = 0.f;
#pragma unroll
        for (int ct = 0; ct < 8; ++ct) {
          float v = acc[rt][ct][r] + blr[ct];
          float hh = xin[(size_t)row * DD + ct * 16 + ar] + gelu_f(v);
          h[ct] = hh; s1 += hh; s2 += hh * hh;
        }
#pragma unroll
        for (int off = 8; off > 0; off >>= 1) {
          s1 += __shfl_xor(s1, off);
          s2 += __shfl_xor(s2, off);
        }
        float mu   = s1 * (1.0f / DD);
        float var  = s2 * (1.0f / DD) - mu * mu;
        float rstd = rsqrtf(var + LN_EPS);
#pragma unroll
        for (int ct = 0; ct < 8; ++ct)
          outp[(size_t)row * DD + ct * 16 + ar] = (h[ct] - mu) * rstd * gr[ct] + br[ct];
      }
    }
  }
}

extern "C" void kernel_launch(void* const* d_in, const int* in_sizes, int n_in,
                              void* d_out, int out_size, void* d_ws, size_t ws_size,
                              hipStream_t stream) {
  const float* x     = (const float*)d_in[0];
  const void*  ei    = d_in[1];
  const float* Wl    = (const float*)d_in[2];
  const float* bl    = (const float*)d_in[3];
  const float* Wr    = (const float*)d_in[4];
  const float* gamma = (const float*)d_in[5];
  const float* beta  = (const float*)d_in[6];
  float* out = (float*)d_out;
  unsigned short* A = (unsigned short*)d_out;  // bf16 [NN][256], same bytes as out

  size_t lds = (size_t)128 * BTSTRIDE * sizeof(unsigned short);
  hipFuncSetAttribute((const void*)mfma_fused_kernel,
                      hipFuncAttributeMaxDynamicSharedMemorySize, (int)lds);

  const size_t csr_need = (size_t)(3 * NN + NE + 1) * sizeof(int);
  const int mfma_blocks = (NN + 127) / 128;

  if (ws_size >= csr_need) {
    // ---- CSR pull path ----
    int* deg    = (int*)d_ws;            // NN
    int* offs   = deg + NN;              // NN
    int* cursor = offs + NN;             // NN
    int* csr    = cursor + NN;           // NE
    int* flag   = csr + NE;              // 1

    hipMemsetAsync(deg, 0, (size_t)NN * sizeof(int), stream);
    detect_kernel<<<1, 256, 0, stream>>>((const unsigned*)ei, flag);
    hist_kernel<<<(NE + 255) / 256, 256, 0, stream>>>(ei, flag, deg);
    scan_kernel<<<1, 1024, 0, stream>>>(deg, offs, cursor);
    fill_kernel<<<(NE + 255) / 256, 256, 0, stream>>>(ei, flag, cursor, csr);
    xtobf_kernel<<<(NN * DD / 8 + 255) / 256, 256, 0, stream>>>(x, A);
    gather16_kernel<<<NN / 16, 256, 0, stream>>>(offs, deg, csr, A);
    mfma_fused_kernel<<<mfma_blocks, 256, lds, stream>>>(A, x, Wl, bl, Wr,
                                                         gamma, beta, out);
  } else {
    // ---- fallback: atomic scatter path ----
    float* degf = (float*)d_ws;          // NN
    int*   flag = (int*)d_ws + NN;       // 1

    hipMemsetAsync(d_out, 0, (size_t)NN * DD * sizeof(float), stream);
    hipMemsetAsync(d_ws, 0, (size_t)NN * sizeof(float), stream);
    detect_kernel<<<1, 256, 0, stream>>>((const unsigned*)ei, flag);
    scatter_kernel<<<(NE * 32) / 256, 256, 0, stream>>>(x, ei, flag, out, degf);
    convertA_kernel<<<NN / 4, 256, 0, stream>>>(x, degf, out, A);
    mfma_fused_kernel<<<mfma_blocks, 256, lds, stream>>>(A, x, Wl, bl, Wr,
                                                         gamma, beta, out);
  }
}

// Round 5
// 147.728 us; speedup vs baseline: 8.4789x; 1.3556x over previous
//
#include <hip/hip_runtime.h>
#include <hip/hip_bf16.h>

#define NN 40000
#define NE 640000
#define DD 128
#define LN_EPS 1e-5f
#define BTSTRIDE 264   // bf16 elements per BT row (256 + 8 pad)

typedef __attribute__((ext_vector_type(8))) short short8;
typedef __attribute__((ext_vector_type(4))) unsigned short ushort4v;
typedef __attribute__((ext_vector_type(4))) float f32x4;

// ---------- helpers ----------
__device__ inline unsigned short f2bf(float f) {
  union { float f; unsigned u; } v; v.f = f;
  unsigned r = v.u + 0x7FFFu + ((v.u >> 16) & 1u);  // round-to-nearest-even
  return (unsigned short)(r >> 16);
}

__device__ inline float bf2f(unsigned short b) {
  union { unsigned u; float f; } c;
  c.u = ((unsigned)b) << 16;
  return c.f;
}

__device__ inline float gelu_f(float v) {
  return 0.5f * v * (1.0f + erff(v * 0.70710678118654752440f));
}

// ---------- kernel 0: detect int32 vs int64 edge_index; zero the allocator ----------
__global__ void detect_kernel(const unsigned* __restrict__ ei, int* __restrict__ flag,
                              int* __restrict__ total) {
  __shared__ int nz;
  if (threadIdx.x == 0) nz = 0;
  __syncthreads();
  if (ei[2u * threadIdx.x + 1u] != 0u) nz = 1;  // benign race, all write 1
  __syncthreads();
  if (threadIdx.x == 0) { *flag = nz; *total = 0; }
}

__device__ inline void load_edge(const void* ei, int use32, unsigned e, int& src, int& dst) {
  if (use32) {
    const int* p = (const int*)ei;
    src = p[e]; dst = p[NE + e];
  } else {
    const long long* p = (const long long*)ei;
    src = (int)p[e]; dst = (int)p[NE + e];
  }
}

// ---------- CSR build ----------
__global__ __launch_bounds__(256)
void hist_kernel(const void* __restrict__ ei, const int* __restrict__ flag,
                 int* __restrict__ deg) {
  unsigned e = blockIdx.x * 256u + threadIdx.x;
  if (e >= NE) return;
  int dst = *flag ? ((const int*)ei)[NE + e] : (int)((const long long*)ei)[NE + e];
  atomicAdd(&deg[dst], 1);
}

// wave-aggregated segment allocation: offs need NOT be ordered, only disjoint.
__global__ __launch_bounds__(256)
void alloc_kernel(const int* __restrict__ deg, int* __restrict__ offs,
                  int* __restrict__ cursor, int* __restrict__ total) {
  const int node = blockIdx.x * 256 + threadIdx.x;
  const int lane = threadIdx.x & 63;
  int d = (node < NN) ? deg[node] : 0;
  // inclusive wave prefix-scan
  int inc = d;
#pragma unroll
  for (int off = 1; off < 64; off <<= 1) {
    int v = __shfl_up(inc, off);
    if (lane >= off) inc += v;
  }
  int excl = inc - d;
  int wtot = __shfl(inc, 63);
  int base = 0;
  if (lane == 63) base = atomicAdd(total, wtot);
  base = __shfl(base, 63);
  if (node < NN) {
    offs[node]   = base + excl;
    cursor[node] = base + excl;
  }
}

__global__ __launch_bounds__(256)
void fill_kernel(const void* __restrict__ ei, const int* __restrict__ flag,
                 int* __restrict__ cursor, int* __restrict__ csr) {
  unsigned e = blockIdx.x * 256u + threadIdx.x;
  if (e >= NE) return;
  int src, dst;
  load_edge(ei, *flag, e, src, dst);
  int pos = atomicAdd(&cursor[dst], 1);
  csr[pos] = src;
}

// ---------- x -> bf16 into A's x-half (A[node][128..256]) ----------
__global__ __launch_bounds__(256)
void xtobf_kernel(const float* __restrict__ x, unsigned short* __restrict__ A) {
  size_t gid = (size_t)blockIdx.x * 256 + threadIdx.x;
  size_t e0 = gid * 8;                  // 8 elements per thread
  int node = (int)(e0 >> 7);
  int k = (int)(e0 & 127);
  float4 a = *(const float4*)(x + e0);
  float4 b = *(const float4*)(x + e0 + 4);
  short8 o;
  o[0] = (short)f2bf(a.x); o[1] = (short)f2bf(a.y);
  o[2] = (short)f2bf(a.z); o[3] = (short)f2bf(a.w);
  o[4] = (short)f2bf(b.x); o[5] = (short)f2bf(b.y);
  o[6] = (short)f2bf(b.z); o[7] = (short)f2bf(b.w);
  *(short8*)(A + (size_t)node * 256 + 128 + k) = o;
}

// ---------- gather: 16 lanes per node, bf16 rows from A's x-half ----------
__global__ __launch_bounds__(256)
void gather16_kernel(const int* __restrict__ offs, const int* __restrict__ deg,
                     const int* __restrict__ csr, unsigned short* __restrict__ A) {
  const int grp = threadIdx.x >> 4;
  const int l16 = threadIdx.x & 15;
  const int node = blockIdx.x * 16 + grp;
  const int beg = offs[node];
  const int d = deg[node];
  float acc[8];
#pragma unroll
  for (int j = 0; j < 8; ++j) acc[j] = 0.f;
  const unsigned short* base = A + 128 + l16 * 8;  // x-half
  int idx = (d > 0) ? csr[beg] : 0;
  for (int i = 0; i < d; ++i) {
    int nidx = (i + 1 < d) ? csr[beg + i + 1] : 0;
    short8 v = *(const short8*)(base + (size_t)idx * 256);
#pragma unroll
    for (int j = 0; j < 8; ++j) acc[j] += bf2f((unsigned short)v[j]);
    idx = nidx;
  }
  float r = 1.0f / fmaxf((float)d, 1.0f);
  short8 o;
#pragma unroll
  for (int j = 0; j < 8; ++j) o[j] = (short)f2bf(acc[j] * r);
  *(short8*)(A + (size_t)node * 256 + l16 * 8) = o;
}

// ---------- fallback: atomic scatter + in-place convert to A ----------
__global__ __launch_bounds__(256)
void scatter_kernel(const float* __restrict__ x, const void* __restrict__ ei,
                    const int* __restrict__ flag,
                    float* summed, float* __restrict__ deg) {
  unsigned gid = blockIdx.x * 256u + threadIdx.x;
  unsigned e = gid >> 5;
  unsigned part = gid & 31u;
  if (e >= NE) return;
  int src, dst;
  load_edge(ei, *flag, e, src, dst);
  float4 v = *(const float4*)(x + (size_t)src * DD + part * 4u);
  float* b = summed + (size_t)dst * DD + part * 4u;
  unsafeAtomicAdd(b + 0, v.x);
  unsafeAtomicAdd(b + 1, v.y);
  unsafeAtomicAdd(b + 2, v.z);
  unsafeAtomicAdd(b + 3, v.w);
  if (part == 0) unsafeAtomicAdd(deg + dst, 1.0f);
}

__global__ __launch_bounds__(256)
void convertA_kernel(const float* __restrict__ x, const float* __restrict__ degf,
                     float* sum /* aliases A */, unsigned short* A) {
  const int wave = threadIdx.x >> 6;
  const int lane = threadIdx.x & 63;
  const int node = blockIdx.x * 4 + wave;
  float2 sv = *(const float2*)(sum + (size_t)node * DD + lane * 2);
  float r = 1.0f / fmaxf(degf[node], 1.0f);
  float2 xv = *(const float2*)(x + (size_t)node * DD + lane * 2);
  asm volatile("" ::: "memory");  // order loads before aliased stores
  ushort2 m; m.x = f2bf(sv.x * r); m.y = f2bf(sv.y * r);
  ushort2 xo; xo.x = f2bf(xv.x); xo.y = f2bf(xv.y);
  *(ushort2*)(A + (size_t)node * 256 + lane * 2) = m;
  *(ushort2*)(A + (size_t)node * 256 + DD + lane * 2) = xo;
}

// ---------- MFMA fused: A[128 rows]x[256] @ BT^T + bias -> GELU -> +x -> LN ----------
__global__ __launch_bounds__(256, 2)
void mfma_fused_kernel(const unsigned short* __restrict__ A,
                       const float* __restrict__ xin,
                       const float* __restrict__ Wl,
                       const float* __restrict__ blv,
                       const float* __restrict__ Wr,
                       const float* __restrict__ gammav,
                       const float* __restrict__ betav,
                       float* __restrict__ outp) {
  extern __shared__ unsigned short BT[];  // [128][BTSTRIDE]
  const int tid = threadIdx.x;

  // stage W^T (stacked [Wl|Wr] along k) as bf16, vectorized ds_write_b64
  for (int i = tid; i < 128 * 32; i += 256) {
    int j  = i >> 5;
    int kc = (i & 31) << 2;
    float4 wl = *(const float4*)(Wl + j * DD + kc);
    float4 wr = *(const float4*)(Wr + j * DD + kc);
    ushort4v pl = {f2bf(wl.x), f2bf(wl.y), f2bf(wl.z), f2bf(wl.w)};
    ushort4v pr = {f2bf(wr.x), f2bf(wr.y), f2bf(wr.z), f2bf(wr.w)};
    *(ushort4v*)(BT + j * BTSTRIDE + kc) = pl;
    *(ushort4v*)(BT + j * BTSTRIDE + DD + kc) = pr;
  }
  __syncthreads();

  const int wv = tid >> 6;
  const int l  = tid & 63;
  const int row0 = blockIdx.x * 128 + wv * 32;
  const int ar = l & 15;     // row/col-within-tile index
  const int kg = l >> 4;     // k-group (8 contiguous k per group)

  f32x4 acc[2][8];
#pragma unroll
  for (int rt = 0; rt < 2; ++rt)
#pragma unroll
    for (int ct = 0; ct < 8; ++ct)
      acc[rt][ct] = (f32x4){0.f, 0.f, 0.f, 0.f};

  const int r0 = min(row0 + ar, NN - 1);
  const int r1 = min(row0 + 16 + ar, NN - 1);

#pragma unroll
  for (int ks = 0; ks < 8; ++ks) {
    const int kb = ks * 32 + kg * 8;
    short8 a0 = *(const short8*)(A + (size_t)r0 * 256 + kb);
    short8 a1 = *(const short8*)(A + (size_t)r1 * 256 + kb);
#pragma unroll
    for (int ct = 0; ct < 8; ++ct) {
      short8 b = *(const short8*)(BT + (ct * 16 + ar) * BTSTRIDE + kb);
      acc[0][ct] = __builtin_amdgcn_mfma_f32_16x16x32_bf16(a0, b, acc[0][ct], 0, 0, 0);
      acc[1][ct] = __builtin_amdgcn_mfma_f32_16x16x32_bf16(a1, b, acc[1][ct], 0, 0, 0);
    }
  }

  float blr[8], gr[8], br[8];
#pragma unroll
  for (int ct = 0; ct < 8; ++ct) {
    blr[ct] = blv[ct * 16 + ar];
    gr[ct]  = gammav[ct * 16 + ar];
    br[ct]  = betav[ct * 16 + ar];
  }

#pragma unroll
  for (int rt = 0; rt < 2; ++rt) {
#pragma unroll
    for (int r = 0; r < 4; ++r) {
      const int row = row0 + rt * 16 + kg * 4 + r;
      if (row < NN) {
        float h[8];
        float s1 = 0.f, s2 = 0.f;
#pragma unroll
        for (int ct = 0; ct < 8; ++ct) {
          float v = acc[rt][ct][r] + blr[ct];
          float hh = xin[(size_t)row * DD + ct * 16 + ar] + gelu_f(v);
          h[ct] = hh; s1 += hh; s2 += hh * hh;
        }
#pragma unroll
        for (int off = 8; off > 0; off >>= 1) {
          s1 += __shfl_xor(s1, off);
          s2 += __shfl_xor(s2, off);
        }
        float mu   = s1 * (1.0f / DD);
        float var  = s2 * (1.0f / DD) - mu * mu;
        float rstd = rsqrtf(var + LN_EPS);
#pragma unroll
        for (int ct = 0; ct < 8; ++ct)
          outp[(size_t)row * DD + ct * 16 + ar] = (h[ct] - mu) * rstd * gr[ct] + br[ct];
      }
    }
  }
}

extern "C" void kernel_launch(void* const* d_in, const int* in_sizes, int n_in,
                              void* d_out, int out_size, void* d_ws, size_t ws_size,
                              hipStream_t stream) {
  const float* x     = (const float*)d_in[0];
  const void*  ei    = d_in[1];
  const float* Wl    = (const float*)d_in[2];
  const float* bl    = (const float*)d_in[3];
  const float* Wr    = (const float*)d_in[4];
  const float* gamma = (const float*)d_in[5];
  const float* beta  = (const float*)d_in[6];
  float* out = (float*)d_out;
  unsigned short* A = (unsigned short*)d_out;  // bf16 [NN][256], same bytes as out

  size_t lds = (size_t)128 * BTSTRIDE * sizeof(unsigned short);
  hipFuncSetAttribute((const void*)mfma_fused_kernel,
                      hipFuncAttributeMaxDynamicSharedMemorySize, (int)lds);

  const size_t csr_need = (size_t)(3 * NN + NE + 2) * sizeof(int);
  const int mfma_blocks = (NN + 127) / 128;

  if (ws_size >= csr_need) {
    // ---- CSR pull path ----
    int* deg    = (int*)d_ws;            // NN
    int* offs   = deg + NN;              // NN
    int* cursor = offs + NN;             // NN
    int* csr    = cursor + NN;           // NE
    int* flag   = csr + NE;              // 1
    int* total  = flag + 1;              // 1 (allocation cursor)

    hipMemsetAsync(deg, 0, (size_t)NN * sizeof(int), stream);
    detect_kernel<<<1, 256, 0, stream>>>((const unsigned*)ei, flag, total);
    hist_kernel<<<(NE + 255) / 256, 256, 0, stream>>>(ei, flag, deg);
    alloc_kernel<<<(NN + 255) / 256, 256, 0, stream>>>(deg, offs, cursor, total);
    fill_kernel<<<(NE + 255) / 256, 256, 0, stream>>>(ei, flag, cursor, csr);
    xtobf_kernel<<<(NN * DD / 8 + 255) / 256, 256, 0, stream>>>(x, A);
    gather16_kernel<<<NN / 16, 256, 0, stream>>>(offs, deg, csr, A);
    mfma_fused_kernel<<<mfma_blocks, 256, lds, stream>>>(A, x, Wl, bl, Wr,
                                                         gamma, beta, out);
  } else {
    // ---- fallback: atomic scatter path ----
    float* degf = (float*)d_ws;          // NN
    int*   flag = (int*)d_ws + NN;       // 1
    int*   total = flag + 1;             // 1 (unused here)

    hipMemsetAsync(d_out, 0, (size_t)NN * DD * sizeof(float), stream);
    hipMemsetAsync(d_ws, 0, (size_t)NN * sizeof(float), stream);
    detect_kernel<<<1, 256, 0, stream>>>((const unsigned*)ei, flag, total);
    scatter_kernel<<<(NE * 32) / 256, 256, 0, stream>>>(x, ei, flag, out, degf);
    convertA_kernel<<<NN / 4, 256, 0, stream>>>(x, degf, out, A);
    mfma_fused_kernel<<<mfma_blocks, 256, lds, stream>>>(A, x, Wl, bl, Wr,
                                                         gamma, beta, out);
  }
}

// Round 6
// 140.742 us; speedup vs baseline: 8.8998x; 1.0496x over previous
//
#include <hip/hip_runtime.h>
#include <hip/hip_bf16.h>

#define NN 40000
#define NE 640000
#define DD 128
#define LN_EPS 1e-5f
#define BTSTRIDE 264   // bf16 elements per BT row (256 + 8 pad)

typedef __attribute__((ext_vector_type(8))) short short8;
typedef __attribute__((ext_vector_type(4))) unsigned short ushort4v;
typedef __attribute__((ext_vector_type(4))) float f32x4;

// ---------- helpers ----------
__device__ inline unsigned short f2bf(float f) {
  union { float f; unsigned u; } v; v.f = f;
  unsigned r = v.u + 0x7FFFu + ((v.u >> 16) & 1u);  // round-to-nearest-even
  return (unsigned short)(r >> 16);
}

__device__ inline float bf2f(unsigned short b) {
  union { unsigned u; float f; } c;
  c.u = ((unsigned)b) << 16;
  return c.f;
}

__device__ inline float gelu_f(float v) {
  return 0.5f * v * (1.0f + erff(v * 0.70710678118654752440f));
}

// ---------- kernel 0: zero deg + detect int32/int64 + reset allocator ----------
// grid 157 x 256 covers 40192 >= NN. Block 0 also detects the index dtype.
__global__ __launch_bounds__(256)
void zero_detect_kernel(const unsigned* __restrict__ ei, int* __restrict__ deg,
                        int* __restrict__ flag, int* __restrict__ total) {
  const int i = blockIdx.x * 256 + threadIdx.x;
  if (i < NN) deg[i] = 0;
  if (blockIdx.x == 0) {
    __shared__ int nz;
    if (threadIdx.x == 0) nz = 0;
    __syncthreads();
    if (ei[2u * threadIdx.x + 1u] != 0u) nz = 1;  // benign race, all write 1
    __syncthreads();
    if (threadIdx.x == 0) { *flag = nz; *total = 0; }
  }
}

__device__ inline void load_edge(const void* ei, int use32, unsigned e, int& src, int& dst) {
  if (use32) {
    const int* p = (const int*)ei;
    src = p[e]; dst = p[NE + e];
  } else {
    const long long* p = (const long long*)ei;
    src = (int)p[e]; dst = (int)p[NE + e];
  }
}

// ---------- hist + x->bf16 merged (NE == NN*DD/8 exactly) ----------
__global__ __launch_bounds__(256)
void hist_x_kernel(const void* __restrict__ ei, const int* __restrict__ flag,
                   int* __restrict__ deg, const float* __restrict__ x,
                   unsigned short* __restrict__ A) {
  const unsigned gid = blockIdx.x * 256u + threadIdx.x;   // 0..NE-1
  // histogram of dst
  int dst = *flag ? ((const int*)ei)[NE + gid] : (int)((const long long*)ei)[NE + gid];
  atomicAdd(&deg[dst], 1);
  // convert 8 fp32 of x -> bf16 into A's x-half
  const size_t e0 = (size_t)gid * 8;
  const int node = (int)(e0 >> 7);
  const int k = (int)(e0 & 127);
  float4 a = *(const float4*)(x + e0);
  float4 b = *(const float4*)(x + e0 + 4);
  short8 o;
  o[0] = (short)f2bf(a.x); o[1] = (short)f2bf(a.y);
  o[2] = (short)f2bf(a.z); o[3] = (short)f2bf(a.w);
  o[4] = (short)f2bf(b.x); o[5] = (short)f2bf(b.y);
  o[6] = (short)f2bf(b.z); o[7] = (short)f2bf(b.w);
  *(short8*)(A + (size_t)node * 256 + 128 + k) = o;
}

// wave-aggregated segment allocation: offs need NOT be ordered, only disjoint.
__global__ __launch_bounds__(256)
void alloc_kernel(const int* __restrict__ deg, int* __restrict__ offs,
                  int* __restrict__ cursor, int* __restrict__ total) {
  const int node = blockIdx.x * 256 + threadIdx.x;
  const int lane = threadIdx.x & 63;
  int d = (node < NN) ? deg[node] : 0;
  int inc = d;
#pragma unroll
  for (int off = 1; off < 64; off <<= 1) {
    int v = __shfl_up(inc, off);
    if (lane >= off) inc += v;
  }
  int excl = inc - d;
  int wtot = __shfl(inc, 63);
  int base = 0;
  if (lane == 63) base = atomicAdd(total, wtot);
  base = __shfl(base, 63);
  if (node < NN) {
    offs[node]   = base + excl;
    cursor[node] = base + excl;
  }
}

__global__ __launch_bounds__(256)
void fill_kernel(const void* __restrict__ ei, const int* __restrict__ flag,
                 int* __restrict__ cursor, int* __restrict__ csr) {
  unsigned e = blockIdx.x * 256u + threadIdx.x;
  if (e >= NE) return;
  int src, dst;
  load_edge(ei, *flag, e, src, dst);
  int pos = atomicAdd(&cursor[dst], 1);
  csr[pos] = src;
}

// ---------- gather: 16 lanes per node, bf16 rows from A's x-half ----------
__global__ __launch_bounds__(256)
void gather16_kernel(const int* __restrict__ offs, const int* __restrict__ deg,
                     const int* __restrict__ csr, unsigned short* __restrict__ A) {
  const int grp = threadIdx.x >> 4;
  const int l16 = threadIdx.x & 15;
  const int node = blockIdx.x * 16 + grp;
  const int beg = offs[node];
  const int d = deg[node];
  float acc[8];
#pragma unroll
  for (int j = 0; j < 8; ++j) acc[j] = 0.f;
  const unsigned short* base = A + 128 + l16 * 8;  // x-half
  int idx = (d > 0) ? csr[beg] : 0;
  for (int i = 0; i < d; ++i) {
    int nidx = (i + 1 < d) ? csr[beg + i + 1] : 0;
    short8 v = *(const short8*)(base + (size_t)idx * 256);
#pragma unroll
    for (int j = 0; j < 8; ++j) acc[j] += bf2f((unsigned short)v[j]);
    idx = nidx;
  }
  float r = 1.0f / fmaxf((float)d, 1.0f);
  short8 o;
#pragma unroll
  for (int j = 0; j < 8; ++j) o[j] = (short)f2bf(acc[j] * r);
  *(short8*)(A + (size_t)node * 256 + l16 * 8) = o;
}

// ---------- fallback: atomic scatter + in-place convert to A ----------
__global__ __launch_bounds__(256)
void scatter_kernel(const float* __restrict__ x, const void* __restrict__ ei,
                    const int* __restrict__ flag,
                    float* summed, float* __restrict__ deg) {
  unsigned gid = blockIdx.x * 256u + threadIdx.x;
  unsigned e = gid >> 5;
  unsigned part = gid & 31u;
  if (e >= NE) return;
  int src, dst;
  load_edge(ei, *flag, e, src, dst);
  float4 v = *(const float4*)(x + (size_t)src * DD + part * 4u);
  float* b = summed + (size_t)dst * DD + part * 4u;
  unsafeAtomicAdd(b + 0, v.x);
  unsafeAtomicAdd(b + 1, v.y);
  unsafeAtomicAdd(b + 2, v.z);
  unsafeAtomicAdd(b + 3, v.w);
  if (part == 0) unsafeAtomicAdd(deg + dst, 1.0f);
}

__global__ __launch_bounds__(256)
void convertA_kernel(const float* __restrict__ x, const float* __restrict__ degf,
                     float* sum /* aliases A */, unsigned short* A) {
  const int wave = threadIdx.x >> 6;
  const int lane = threadIdx.x & 63;
  const int node = blockIdx.x * 4 + wave;
  float2 sv = *(const float2*)(sum + (size_t)node * DD + lane * 2);
  float r = 1.0f / fmaxf(degf[node], 1.0f);
  float2 xv = *(const float2*)(x + (size_t)node * DD + lane * 2);
  asm volatile("" ::: "memory");  // order loads before aliased stores
  ushort2 m; m.x = f2bf(sv.x * r); m.y = f2bf(sv.y * r);
  ushort2 xo; xo.x = f2bf(xv.x); xo.y = f2bf(xv.y);
  *(ushort2*)(A + (size_t)node * 256 + lane * 2) = m;
  *(ushort2*)(A + (size_t)node * 256 + DD + lane * 2) = xo;
}

// ---------- MFMA fused: A[128 rows]x[256] @ BT^T + bias -> GELU -> +x -> LN ----------
__global__ __launch_bounds__(256, 2)
void mfma_fused_kernel(const unsigned short* __restrict__ A,
                       const float* __restrict__ xin,
                       const float* __restrict__ Wl,
                       const float* __restrict__ blv,
                       const float* __restrict__ Wr,
                       const float* __restrict__ gammav,
                       const float* __restrict__ betav,
                       float* __restrict__ outp) {
  extern __shared__ unsigned short BT[];  // [128][BTSTRIDE]
  const int tid = threadIdx.x;

  for (int i = tid; i < 128 * 32; i += 256) {
    int j  = i >> 5;
    int kc = (i & 31) << 2;
    float4 wl = *(const float4*)(Wl + j * DD + kc);
    float4 wr = *(const float4*)(Wr + j * DD + kc);
    ushort4v pl = {f2bf(wl.x), f2bf(wl.y), f2bf(wl.z), f2bf(wl.w)};
    ushort4v pr = {f2bf(wr.x), f2bf(wr.y), f2bf(wr.z), f2bf(wr.w)};
    *(ushort4v*)(BT + j * BTSTRIDE + kc) = pl;
    *(ushort4v*)(BT + j * BTSTRIDE + DD + kc) = pr;
  }
  __syncthreads();

  const int wv = tid >> 6;
  const int l  = tid & 63;
  const int row0 = blockIdx.x * 128 + wv * 32;
  const int ar = l & 15;     // row/col-within-tile index
  const int kg = l >> 4;     // k-group (8 contiguous k per group)

  f32x4 acc[2][8];
#pragma unroll
  for (int rt = 0; rt < 2; ++rt)
#pragma unroll
    for (int ct = 0; ct < 8; ++ct)
      acc[rt][ct] = (f32x4){0.f, 0.f, 0.f, 0.f};

  const int r0 = min(row0 + ar, NN - 1);
  const int r1 = min(row0 + 16 + ar, NN - 1);

#pragma unroll
  for (int ks = 0; ks < 8; ++ks) {
    const int kb = ks * 32 + kg * 8;
    short8 a0 = *(const short8*)(A + (size_t)r0 * 256 + kb);
    short8 a1 = *(const short8*)(A + (size_t)r1 * 256 + kb);
#pragma unroll
    for (int ct = 0; ct < 8; ++ct) {
      short8 b = *(const short8*)(BT + (ct * 16 + ar) * BTSTRIDE + kb);
      acc[0][ct] = __builtin_amdgcn_mfma_f32_16x16x32_bf16(a0, b, acc[0][ct], 0, 0, 0);
      acc[1][ct] = __builtin_amdgcn_mfma_f32_16x16x32_bf16(a1, b, acc[1][ct], 0, 0, 0);
    }
  }

  float blr[8], gr[8], br[8];
#pragma unroll
  for (int ct = 0; ct < 8; ++ct) {
    blr[ct] = blv[ct * 16 + ar];
    gr[ct]  = gammav[ct * 16 + ar];
    br[ct]  = betav[ct * 16 + ar];
  }

#pragma unroll
  for (int rt = 0; rt < 2; ++rt) {
#pragma unroll
    for (int r = 0; r < 4; ++r) {
      const int row = row0 + rt * 16 + kg * 4 + r;
      if (row < NN) {
        float h[8];
        float s1 = 0.f, s2 = 0.f;
#pragma unroll
        for (int ct = 0; ct < 8; ++ct) {
          float v = acc[rt][ct][r] + blr[ct];
          float hh = xin[(size_t)row * DD + ct * 16 + ar] + gelu_f(v);
          h[ct] = hh; s1 += hh; s2 += hh * hh;
        }
#pragma unroll
        for (int off = 8; off > 0; off >>= 1) {
          s1 += __shfl_xor(s1, off);
          s2 += __shfl_xor(s2, off);
        }
        float mu   = s1 * (1.0f / DD);
        float var  = s2 * (1.0f / DD) - mu * mu;
        float rstd = rsqrtf(var + LN_EPS);
#pragma unroll
        for (int ct = 0; ct < 8; ++ct)
          outp[(size_t)row * DD + ct * 16 + ar] = (h[ct] - mu) * rstd * gr[ct] + br[ct];
      }
    }
  }
}

extern "C" void kernel_launch(void* const* d_in, const int* in_sizes, int n_in,
                              void* d_out, int out_size, void* d_ws, size_t ws_size,
                              hipStream_t stream) {
  const float* x     = (const float*)d_in[0];
  const void*  ei    = d_in[1];
  const float* Wl    = (const float*)d_in[2];
  const float* bl    = (const float*)d_in[3];
  const float* Wr    = (const float*)d_in[4];
  const float* gamma = (const float*)d_in[5];
  const float* beta  = (const float*)d_in[6];
  float* out = (float*)d_out;
  unsigned short* A = (unsigned short*)d_out;  // bf16 [NN][256], same bytes as out

  size_t lds = (size_t)128 * BTSTRIDE * sizeof(unsigned short);
  hipFuncSetAttribute((const void*)mfma_fused_kernel,
                      hipFuncAttributeMaxDynamicSharedMemorySize, (int)lds);

  const size_t csr_need = (size_t)(3 * NN + NE + 2) * sizeof(int);
  const int mfma_blocks = (NN + 127) / 128;

  if (ws_size >= csr_need) {
    // ---- CSR pull path (no memset dispatches) ----
    int* deg    = (int*)d_ws;            // NN
    int* offs   = deg + NN;              // NN
    int* cursor = offs + NN;             // NN
    int* csr    = cursor + NN;           // NE
    int* flag   = csr + NE;              // 1
    int* total  = flag + 1;              // 1 (allocation cursor)

    zero_detect_kernel<<<(NN + 255) / 256, 256, 0, stream>>>((const unsigned*)ei,
                                                             deg, flag, total);
    hist_x_kernel<<<NE / 256, 256, 0, stream>>>(ei, flag, deg, x, A);
    alloc_kernel<<<(NN + 255) / 256, 256, 0, stream>>>(deg, offs, cursor, total);
    fill_kernel<<<(NE + 255) / 256, 256, 0, stream>>>(ei, flag, cursor, csr);
    gather16_kernel<<<NN / 16, 256, 0, stream>>>(offs, deg, csr, A);
    mfma_fused_kernel<<<mfma_blocks, 256, lds, stream>>>(A, x, Wl, bl, Wr,
                                                         gamma, beta, out);
  } else {
    // ---- fallback: atomic scatter path ----
    float* degf = (float*)d_ws;          // NN
    int*   flag = (int*)d_ws + NN;       // 1
    int*   total = flag + 1;             // 1 (unused here)

    hipMemsetAsync(d_out, 0, (size_t)NN * DD * sizeof(float), stream);
    hipMemsetAsync(d_ws, 0, (size_t)NN * sizeof(float), stream);
    zero_detect_kernel<<<(NN + 255) / 256, 256, 0, stream>>>((const unsigned*)ei,
                                                             (int*)d_ws + NN + 2,
                                                             flag, total);
    scatter_kernel<<<(NE * 32) / 256, 256, 0, stream>>>(x, ei, flag, out, degf);
    convertA_kernel<<<NN / 4, 256, 0, stream>>>(x, degf, out, A);
    mfma_fused_kernel<<<mfma_blocks, 256, lds, stream>>>(A, x, Wl, bl, Wr,
                                                         gamma, beta, out);
  }
}

// Round 7
// 123.757 us; speedup vs baseline: 10.1212x; 1.1372x over previous
//
#include <hip/hip_runtime.h>
#include <hip/hip_bf16.h>

#define NN 40000
#define NE 640000
#define DD 128
#define LN_EPS 1e-5f
#define BTSTRIDE 264   // bf16 elements per BT row (256 + 8 pad)
#define FPT 4          // edges per thread in fill_kernel

typedef __attribute__((ext_vector_type(8))) short short8;
typedef __attribute__((ext_vector_type(4))) unsigned short ushort4v;
typedef __attribute__((ext_vector_type(4))) float f32x4;

// ---------- helpers ----------
__device__ inline unsigned short f2bf(float f) {
  union { float f; unsigned u; } v; v.f = f;
  unsigned r = v.u + 0x7FFFu + ((v.u >> 16) & 1u);  // round-to-nearest-even
  return (unsigned short)(r >> 16);
}

__device__ inline float bf2f(unsigned short b) {
  union { unsigned u; float f; } c;
  c.u = ((unsigned)b) << 16;
  return c.f;
}

__device__ inline float gelu_f(float v) {
  return 0.5f * v * (1.0f + erff(v * 0.70710678118654752440f));
}

// ---------- kernel 0: zero deg + detect int32/int64 + reset allocator ----------
__global__ __launch_bounds__(256)
void zero_detect_kernel(const unsigned* __restrict__ ei, int* __restrict__ deg,
                        int* __restrict__ flag, int* __restrict__ total) {
  const int i = blockIdx.x * 256 + threadIdx.x;
  if (i < NN) deg[i] = 0;
  if (blockIdx.x == 0) {
    __shared__ int nz;
    if (threadIdx.x == 0) nz = 0;
    __syncthreads();
    if (ei[2u * threadIdx.x + 1u] != 0u) nz = 1;  // benign race, all write 1
    __syncthreads();
    if (threadIdx.x == 0) { *flag = nz; *total = 0; }
  }
}

__device__ inline void load_edge(const void* ei, int use32, unsigned e, int& src, int& dst) {
  if (use32) {
    const int* p = (const int*)ei;
    src = p[e]; dst = p[NE + e];
  } else {
    const long long* p = (const long long*)ei;
    src = (int)p[e]; dst = (int)p[NE + e];
  }
}

// ---------- hist + x->bf16 merged, 2 edges + 16 converts per thread ----------
__global__ __launch_bounds__(256)
void hist_x_kernel(const void* __restrict__ ei, const int* __restrict__ flag,
                   int* __restrict__ deg, const float* __restrict__ x,
                   unsigned short* __restrict__ A) {
  const unsigned t = blockIdx.x * 256u + threadIdx.x;   // 0..NE/2-1
  const int use32 = *flag;
  // two independent histogram atomics
  int d0, d1;
  if (use32) {
    const int* p = (const int*)ei;
    d0 = p[NE + t]; d1 = p[NE + t + NE / 2];
  } else {
    const long long* p = (const long long*)ei;
    d0 = (int)p[NE + t]; d1 = (int)p[NE + t + NE / 2];
  }
  atomicAdd(&deg[d0], 1);
  atomicAdd(&deg[d1], 1);
  // convert 16 fp32 of x -> bf16 into A's x-half
  const size_t e0 = (size_t)t * 16;
  const int node = (int)(e0 >> 7);
  const int k = (int)(e0 & 127);
  float4 a = *(const float4*)(x + e0);
  float4 b = *(const float4*)(x + e0 + 4);
  float4 c = *(const float4*)(x + e0 + 8);
  float4 d = *(const float4*)(x + e0 + 12);
  short8 o0, o1;
  o0[0] = (short)f2bf(a.x); o0[1] = (short)f2bf(a.y);
  o0[2] = (short)f2bf(a.z); o0[3] = (short)f2bf(a.w);
  o0[4] = (short)f2bf(b.x); o0[5] = (short)f2bf(b.y);
  o0[6] = (short)f2bf(b.z); o0[7] = (short)f2bf(b.w);
  o1[0] = (short)f2bf(c.x); o1[1] = (short)f2bf(c.y);
  o1[2] = (short)f2bf(c.z); o1[3] = (short)f2bf(c.w);
  o1[4] = (short)f2bf(d.x); o1[5] = (short)f2bf(d.y);
  o1[6] = (short)f2bf(d.z); o1[7] = (short)f2bf(d.w);
  *(short8*)(A + (size_t)node * 256 + 128 + k) = o0;
  *(short8*)(A + (size_t)node * 256 + 128 + k + 8) = o1;
}

// wave-aggregated segment allocation: offs need NOT be ordered, only disjoint.
__global__ __launch_bounds__(256)
void alloc_kernel(const int* __restrict__ deg, int* __restrict__ offs,
                  int* __restrict__ cursor, int* __restrict__ total) {
  const int node = blockIdx.x * 256 + threadIdx.x;
  const int lane = threadIdx.x & 63;
  int d = (node < NN) ? deg[node] : 0;
  int inc = d;
#pragma unroll
  for (int off = 1; off < 64; off <<= 1) {
    int v = __shfl_up(inc, off);
    if (lane >= off) inc += v;
  }
  int excl = inc - d;
  int wtot = __shfl(inc, 63);
  int base = 0;
  if (lane == 63) base = atomicAdd(total, wtot);
  base = __shfl(base, 63);
  if (node < NN) {
    offs[node]   = base + excl;
    cursor[node] = base + excl;
  }
}

// ---------- fill: FPT edges per thread, independent atomic+store chains ----------
__global__ __launch_bounds__(256)
void fill_kernel(const void* __restrict__ ei, const int* __restrict__ flag,
                 int* __restrict__ cursor, int* __restrict__ csr) {
  const unsigned t = blockIdx.x * 256u + threadIdx.x;  // 0..NE/FPT-1
  const int use32 = *flag;
  int src[FPT], dst[FPT];
#pragma unroll
  for (int j = 0; j < FPT; ++j) {
    unsigned e = t + j * (NE / FPT);
    if (use32) {
      const int* p = (const int*)ei;
      src[j] = p[e]; dst[j] = p[NE + e];
    } else {
      const long long* p = (const long long*)ei;
      src[j] = (int)p[e]; dst[j] = (int)p[NE + e];
    }
  }
  int pos[FPT];
#pragma unroll
  for (int j = 0; j < FPT; ++j) pos[j] = atomicAdd(&cursor[dst[j]], 1);
#pragma unroll
  for (int j = 0; j < FPT; ++j) csr[pos[j]] = src[j];
}

// ---------- gather: 16 lanes per node, 4 neighbor rows in flight ----------
__global__ __launch_bounds__(256)
void gather16_kernel(const int* __restrict__ offs, const int* __restrict__ deg,
                     const int* __restrict__ csr, unsigned short* __restrict__ A) {
  const int grp = threadIdx.x >> 4;
  const int l16 = threadIdx.x & 15;
  const int node = blockIdx.x * 16 + grp;
  const int beg = offs[node];
  const int d = deg[node];
  float a0[8], a1[8];
#pragma unroll
  for (int j = 0; j < 8; ++j) { a0[j] = 0.f; a1[j] = 0.f; }
  const unsigned short* base = A + 128 + l16 * 8;  // x-half
  int i = 0;
  for (; i + 4 <= d; i += 4) {
    int i0 = csr[beg + i + 0];
    int i1 = csr[beg + i + 1];
    int i2 = csr[beg + i + 2];
    int i3 = csr[beg + i + 3];
    short8 v0 = *(const short8*)(base + (size_t)i0 * 256);
    short8 v1 = *(const short8*)(base + (size_t)i1 * 256);
    short8 v2 = *(const short8*)(base + (size_t)i2 * 256);
    short8 v3 = *(const short8*)(base + (size_t)i3 * 256);
#pragma unroll
    for (int j = 0; j < 8; ++j) {
      a0[j] += bf2f((unsigned short)v0[j]) + bf2f((unsigned short)v2[j]);
      a1[j] += bf2f((unsigned short)v1[j]) + bf2f((unsigned short)v3[j]);
    }
  }
  for (; i < d; ++i) {
    int ix = csr[beg + i];
    short8 v = *(const short8*)(base + (size_t)ix * 256);
#pragma unroll
    for (int j = 0; j < 8; ++j) a0[j] += bf2f((unsigned short)v[j]);
  }
  float r = 1.0f / fmaxf((float)d, 1.0f);
  short8 o;
#pragma unroll
  for (int j = 0; j < 8; ++j) o[j] = (short)f2bf((a0[j] + a1[j]) * r);
  *(short8*)(A + (size_t)node * 256 + l16 * 8) = o;
}

// ---------- fallback: atomic scatter + in-place convert to A ----------
__global__ __launch_bounds__(256)
void scatter_kernel(const float* __restrict__ x, const void* __restrict__ ei,
                    const int* __restrict__ flag,
                    float* summed, float* __restrict__ deg) {
  unsigned gid = blockIdx.x * 256u + threadIdx.x;
  unsigned e = gid >> 5;
  unsigned part = gid & 31u;
  if (e >= NE) return;
  int src, dst;
  load_edge(ei, *flag, e, src, dst);
  float4 v = *(const float4*)(x + (size_t)src * DD + part * 4u);
  float* b = summed + (size_t)dst * DD + part * 4u;
  unsafeAtomicAdd(b + 0, v.x);
  unsafeAtomicAdd(b + 1, v.y);
  unsafeAtomicAdd(b + 2, v.z);
  unsafeAtomicAdd(b + 3, v.w);
  if (part == 0) unsafeAtomicAdd(deg + dst, 1.0f);
}

__global__ __launch_bounds__(256)
void convertA_kernel(const float* __restrict__ x, const float* __restrict__ degf,
                     float* sum /* aliases A */, unsigned short* A) {
  const int wave = threadIdx.x >> 6;
  const int lane = threadIdx.x & 63;
  const int node = blockIdx.x * 4 + wave;
  float2 sv = *(const float2*)(sum + (size_t)node * DD + lane * 2);
  float r = 1.0f / fmaxf(degf[node], 1.0f);
  float2 xv = *(const float2*)(x + (size_t)node * DD + lane * 2);
  asm volatile("" ::: "memory");  // order loads before aliased stores
  ushort2 m; m.x = f2bf(sv.x * r); m.y = f2bf(sv.y * r);
  ushort2 xo; xo.x = f2bf(xv.x); xo.y = f2bf(xv.y);
  *(ushort2*)(A + (size_t)node * 256 + lane * 2) = m;
  *(ushort2*)(A + (size_t)node * 256 + DD + lane * 2) = xo;
}

// ---------- MFMA fused: A[128 rows]x[256] @ BT^T + bias -> GELU -> +x -> LN ----------
__global__ __launch_bounds__(256, 2)
void mfma_fused_kernel(const unsigned short* __restrict__ A,
                       const float* __restrict__ xin,
                       const float* __restrict__ Wl,
                       const float* __restrict__ blv,
                       const float* __restrict__ Wr,
                       const float* __restrict__ gammav,
                       const float* __restrict__ betav,
                       float* __restrict__ outp) {
  extern __shared__ unsigned short BT[];  // [128][BTSTRIDE]
  const int tid = threadIdx.x;

  for (int i = tid; i < 128 * 32; i += 256) {
    int j  = i >> 5;
    int kc = (i & 31) << 2;
    float4 wl = *(const float4*)(Wl + j * DD + kc);
    float4 wr = *(const float4*)(Wr + j * DD + kc);
    ushort4v pl = {f2bf(wl.x), f2bf(wl.y), f2bf(wl.z), f2bf(wl.w)};
    ushort4v pr = {f2bf(wr.x), f2bf(wr.y), f2bf(wr.z), f2bf(wr.w)};
    *(ushort4v*)(BT + j * BTSTRIDE + kc) = pl;
    *(ushort4v*)(BT + j * BTSTRIDE + DD + kc) = pr;
  }
  __syncthreads();

  const int wv = tid >> 6;
  const int l  = tid & 63;
  const int row0 = blockIdx.x * 128 + wv * 32;
  const int ar = l & 15;     // row/col-within-tile index
  const int kg = l >> 4;     // k-group (8 contiguous k per group)

  f32x4 acc[2][8];
#pragma unroll
  for (int rt = 0; rt < 2; ++rt)
#pragma unroll
    for (int ct = 0; ct < 8; ++ct)
      acc[rt][ct] = (f32x4){0.f, 0.f, 0.f, 0.f};

  const int r0 = min(row0 + ar, NN - 1);
  const int r1 = min(row0 + 16 + ar, NN - 1);

#pragma unroll
  for (int ks = 0; ks < 8; ++ks) {
    const int kb = ks * 32 + kg * 8;
    short8 a0 = *(const short8*)(A + (size_t)r0 * 256 + kb);
    short8 a1 = *(const short8*)(A + (size_t)r1 * 256 + kb);
#pragma unroll
    for (int ct = 0; ct < 8; ++ct) {
      short8 b = *(const short8*)(BT + (ct * 16 + ar) * BTSTRIDE + kb);
      acc[0][ct] = __builtin_amdgcn_mfma_f32_16x16x32_bf16(a0, b, acc[0][ct], 0, 0, 0);
      acc[1][ct] = __builtin_amdgcn_mfma_f32_16x16x32_bf16(a1, b, acc[1][ct], 0, 0, 0);
    }
  }

  float blr[8], gr[8], br[8];
#pragma unroll
  for (int ct = 0; ct < 8; ++ct) {
    blr[ct] = blv[ct * 16 + ar];
    gr[ct]  = gammav[ct * 16 + ar];
    br[ct]  = betav[ct * 16 + ar];
  }

#pragma unroll
  for (int rt = 0; rt < 2; ++rt) {
#pragma unroll
    for (int r = 0; r < 4; ++r) {
      const int row = row0 + rt * 16 + kg * 4 + r;
      if (row < NN) {
        float h[8];
        float s1 = 0.f, s2 = 0.f;
#pragma unroll
        for (int ct = 0; ct < 8; ++ct) {
          float v = acc[rt][ct][r] + blr[ct];
          float hh = xin[(size_t)row * DD + ct * 16 + ar] + gelu_f(v);
          h[ct] = hh; s1 += hh; s2 += hh * hh;
        }
#pragma unroll
        for (int off = 8; off > 0; off >>= 1) {
          s1 += __shfl_xor(s1, off);
          s2 += __shfl_xor(s2, off);
        }
        float mu   = s1 * (1.0f / DD);
        float var  = s2 * (1.0f / DD) - mu * mu;
        float rstd = rsqrtf(var + LN_EPS);
#pragma unroll
        for (int ct = 0; ct < 8; ++ct)
          outp[(size_t)row * DD + ct * 16 + ar] = (h[ct] - mu) * rstd * gr[ct] + br[ct];
      }
    }
  }
}

extern "C" void kernel_launch(void* const* d_in, const int* in_sizes, int n_in,
                              void* d_out, int out_size, void* d_ws, size_t ws_size,
                              hipStream_t stream) {
  const float* x     = (const float*)d_in[0];
  const void*  ei    = d_in[1];
  const float* Wl    = (const float*)d_in[2];
  const float* bl    = (const float*)d_in[3];
  const float* Wr    = (const float*)d_in[4];
  const float* gamma = (const float*)d_in[5];
  const float* beta  = (const float*)d_in[6];
  float* out = (float*)d_out;
  unsigned short* A = (unsigned short*)d_out;  // bf16 [NN][256], same bytes as out

  size_t lds = (size_t)128 * BTSTRIDE * sizeof(unsigned short);
  hipFuncSetAttribute((const void*)mfma_fused_kernel,
                      hipFuncAttributeMaxDynamicSharedMemorySize, (int)lds);

  const size_t csr_need = (size_t)(3 * NN + NE + 2) * sizeof(int);
  const int mfma_blocks = (NN + 127) / 128;

  if (ws_size >= csr_need) {
    // ---- CSR pull path (no memset dispatches) ----
    int* deg    = (int*)d_ws;            // NN
    int* offs   = deg + NN;              // NN
    int* cursor = offs + NN;             // NN
    int* csr    = cursor + NN;           // NE
    int* flag   = csr + NE;              // 1
    int* total  = flag + 1;              // 1 (allocation cursor)

    zero_detect_kernel<<<(NN + 255) / 256, 256, 0, stream>>>((const unsigned*)ei,
                                                             deg, flag, total);
    hist_x_kernel<<<NE / 2 / 256, 256, 0, stream>>>(ei, flag, deg, x, A);
    alloc_kernel<<<(NN + 255) / 256, 256, 0, stream>>>(deg, offs, cursor, total);
    fill_kernel<<<NE / FPT / 256, 256, 0, stream>>>(ei, flag, cursor, csr);
    gather16_kernel<<<NN / 16, 256, 0, stream>>>(offs, deg, csr, A);
    mfma_fused_kernel<<<mfma_blocks, 256, lds, stream>>>(A, x, Wl, bl, Wr,
                                                         gamma, beta, out);
  } else {
    // ---- fallback: atomic scatter path ----
    float* degf = (float*)d_ws;          // NN
    int*   flag = (int*)d_ws + NN;       // 1
    int*   total = flag + 1;             // 1 (unused here)

    hipMemsetAsync(d_out, 0, (size_t)NN * DD * sizeof(float), stream);
    hipMemsetAsync(d_ws, 0, (size_t)NN * sizeof(float), stream);
    zero_detect_kernel<<<(NN + 255) / 256, 256, 0, stream>>>((const unsigned*)ei,
                                                             (int*)d_ws + NN + 2,
                                                             flag, total);
    scatter_kernel<<<(NE * 32) / 256, 256, 0, stream>>>(x, ei, flag, out, degf);
    convertA_kernel<<<NN / 4, 256, 0, stream>>>(x, degf, out, A);
    mfma_fused_kernel<<<mfma_blocks, 256, lds, stream>>>(A, x, Wl, bl, Wr,
                                                         gamma, beta, out);
  }
}